// Round 2
// baseline (139.462 us; speedup 1.0000x reference)
//
#include <hip/hip_runtime.h>
#include <hip/hip_bf16.h>

#define B_ 4
#define L_ 1024
#define E_ 256
#define S_ 32

typedef __bf16 bf16x8 __attribute__((ext_vector_type(8)));
typedef float f32x4 __attribute__((ext_vector_type(4)));

__device__ __forceinline__ __bf16 bf_from_bits(unsigned short u) {
    __bf16 b;
    __builtin_memcpy(&b, &u, 2);
    return b;
}

// Split fp32 -> bf16 hi (truncate) + bf16 lo (residual). a ~= hi + lo with
// ~2^-17 rel error when both terms are used in the MFMA product expansion.
__device__ __forceinline__ void load8split(const float* __restrict__ p,
                                           bf16x8& h, bf16x8& l) {
    const float4 x0 = *(const float4*)p;
    const float4 x1 = *(const float4*)(p + 4);
    const float xs[8] = {x0.x, x0.y, x0.z, x0.w, x1.x, x1.y, x1.z, x1.w};
#pragma unroll
    for (int j = 0; j < 8; ++j) {
        const unsigned hb = __float_as_uint(xs[j]) & 0xFFFF0000u;
        h[j] = bf_from_bits((unsigned short)(hb >> 16));
        l[j] = (__bf16)(xs[j] - __uint_as_float(hb));
    }
}

// ===========================================================================
// PATH A kernel 1: Q/K/V projections, out[m,n] = sum_k A[m,k]*W[n,k] + b[n].
// Block 256 = 4 waves; block slab = 32 rows x 256 cols (one matrix, z-dim).
// Wave: 2 M-tiles x 4 N-tiles (8 accumulators) -> 24 MFMA per 6 fragment
// loads per K-step. (~4-5 us; unchanged — not the bottleneck.)
// ===========================================================================
__global__ __launch_bounds__(256, 1) void qkv_gemm2(
    const float* __restrict__ A,
    const float* __restrict__ Wq, const float* __restrict__ bq,
    const float* __restrict__ Wk, const float* __restrict__ bk,
    const float* __restrict__ Wv, const float* __restrict__ bv,
    float* __restrict__ Qo, float* __restrict__ Ko, float* __restrict__ Vo)
{
    const float* Wm;
    const float* bm;
    float* Om;
    const int z = blockIdx.z;
    if (z == 0)      { Wm = Wq; bm = bq; Om = Qo; }
    else if (z == 1) { Wm = Wk; bm = bk; Om = Ko; }
    else             { Wm = Wv; bm = bv; Om = Vo; }

    const int wave = threadIdx.x >> 6;
    const int lane = threadIdx.x & 63;
    const int rsel = lane & 15;
    const int koff = (lane >> 4) * 8;

    const int m0 = blockIdx.x * 32;
    const int nb = wave * 64;

    const float* pa0 = A + (size_t)(m0 + rsel) * 256 + koff;
    const float* pa1 = pa0 + (size_t)16 * 256;
    const float* pw0 = Wm + (size_t)(nb + 0  + rsel) * 256 + koff;
    const float* pw1 = Wm + (size_t)(nb + 16 + rsel) * 256 + koff;
    const float* pw2 = Wm + (size_t)(nb + 32 + rsel) * 256 + koff;
    const float* pw3 = Wm + (size_t)(nb + 48 + rsel) * 256 + koff;

    f32x4 acc[2][4];
#pragma unroll
    for (int mt = 0; mt < 2; ++mt)
#pragma unroll
        for (int nt = 0; nt < 4; ++nt)
            acc[mt][nt] = (f32x4){0.f, 0.f, 0.f, 0.f};

#pragma unroll
    for (int k0 = 0; k0 < 256; k0 += 32) {
        bf16x8 ah[2], al[2], bh[4], bl[4];
        load8split(pa0 + k0, ah[0], al[0]);
        load8split(pa1 + k0, ah[1], al[1]);
        load8split(pw0 + k0, bh[0], bl[0]);
        load8split(pw1 + k0, bh[1], bl[1]);
        load8split(pw2 + k0, bh[2], bl[2]);
        load8split(pw3 + k0, bh[3], bl[3]);
#pragma unroll
        for (int mt = 0; mt < 2; ++mt)
#pragma unroll
            for (int nt = 0; nt < 4; ++nt) {
                acc[mt][nt] = __builtin_amdgcn_mfma_f32_16x16x32_bf16(
                    ah[mt], bh[nt], acc[mt][nt], 0, 0, 0);
                acc[mt][nt] = __builtin_amdgcn_mfma_f32_16x16x32_bf16(
                    ah[mt], bl[nt], acc[mt][nt], 0, 0, 0);
                acc[mt][nt] = __builtin_amdgcn_mfma_f32_16x16x32_bf16(
                    al[mt], bh[nt], acc[mt][nt], 0, 0, 0);
            }
    }

#pragma unroll
    for (int mt = 0; mt < 2; ++mt) {
        const int mrow = m0 + mt * 16 + (lane >> 4) * 4;
#pragma unroll
        for (int nt = 0; nt < 4; ++nt) {
            const int n = nb + nt * 16 + rsel;
            const float bias = bm[n];
#pragma unroll
            for (int r = 0; r < 4; ++r)
                Om[(size_t)(mrow + r) * 256 + n] = acc[mt][nt][r] + bias;
        }
    }
}

// ===========================================================================
// PATH A kernel 2 (v4): windowed per-channel softmax + context + sigmoid^2.
// Changes vs v3 (aft_stage2c) — stage-2 is LDS-throughput-bound (2 b128+1
// per tap = 48B/thread/tap, ~793 MB total LDS reads):
//  - V is NOT staged in LDS. Per-block V slab is 12 KB (L1-resident); vv is
//    read straight from global so the VMEM pipe serves it in parallel with
//    the DS pipe. LDS reads/tap: 3 -> 2 (-33% DS traffic); LDS 37 -> 23 KB.
//  - exp2 rewrite: qs = qv*log2e precomputed; tap does add+mul+v_exp_f32
//    (saves one mul per exp, 252/thread).
//  - grid is 1024 blocks = exactly 4/CU, so occupancy capacity beyond 4 is
//    unreachable; keep __launch_bounds__(256,4) (VGPR<=128, no spill with
//    unroll-7 window).
// ===========================================================================
#define TI3 32
#define CH3 32
#define HB3 96          // TI3 + 2*S halo rows
#define PS3 36          // padded LDS stride (floats); banks rotate by 4/row

__global__ __launch_bounds__(256, 4) void aft_stage2d(
    const float* __restrict__ Q, const float* __restrict__ K,
    const float* __restrict__ V, const float* __restrict__ pb,
    float* __restrict__ out)
{
    __shared__ float Kw[HB3][PS3];        // 13824 B
    __shared__ float Pw[2 * S_ + 1][PS3]; //  9360 B  (total 23184 B)

    const int tid = threadIdx.x;
    const int b  = blockIdx.y;
    const int i0 = blockIdx.x * TI3;
    const int c0 = blockIdx.z * CH3;

    const int cq = (tid & 7) * 4;   // channel quad within tile
    const int rr = tid >> 3;        // row within tile, 0..31
    const int i  = i0 + rr;

    // Issue the Q read before staging so it completes under the barrier.
    const float4 qv = *(const float4*)(Q + ((size_t)b * L_ + i) * E_ + c0 + cq);

    const float* Kb   = K + (size_t)b * L_ * E_;
    const float* Vcol = V + (size_t)b * L_ * E_ + c0 + cq;  // per-thread V column

    // ---- stage K halo rows (96 rows x 32 ch) ----
    for (int idx = tid; idx < HB3 * 8; idx += 256) {
        const int r = idx >> 3;
        const int c = (idx & 7) * 4;
        int j = i0 - S_ + r;
        j = j < 0 ? 0 : (j > L_ - 1 ? L_ - 1 : j);   // clamped rows get m=0
        *(float4*)&Kw[r][c] = *(const float4*)(Kb + (size_t)j * E_ + c0 + c);
    }
    // ---- stage pos_bias slice (65 rows x 32 ch) ----
    for (int idx = tid; idx < (2 * S_ + 1) * 8; idx += 256) {
        const int r = idx >> 3;
        const int c = (idx & 7) * 4;
        *(float4*)&Pw[r][c] = *(const float4*)(pb + (size_t)r * E_ + c0 + c);
    }
    __syncthreads();

    // Precompute q*log2(e) so each tap is add+mul+v_exp_f32 (exp2 domain).
    const float LOG2E = 1.44269504088896340736f;
    const float qs0 = qv.x * LOG2E, qs1 = qv.y * LOG2E;
    const float qs2 = qv.z * LOG2E, qs3 = qv.w * LOG2E;

    // ---- peeled edge taps: w=0 and w=2S have K zeroed by the strict mask,
    //      so logit = valid ? 0 : NEG  =>  e = valid ? 1 : 0.
    const int jA = (i - S_ < 0) ? 0 : (i - S_);
    const int jB = (i + S_ > L_ - 1) ? (L_ - 1) : (i + S_);
    const float mA = (i >= S_) ? 1.f : 0.f;             // w = 0
    const float mB = (i <= L_ - 1 - S_) ? 1.f : 0.f;    // w = 2S
    const float4 vA = *(const float4*)(Vcol + (size_t)jA * E_);
    const float4 vB = *(const float4*)(Vcol + (size_t)jB * E_);

    float den0 = mA + mB, den1 = mA + mB, den2 = mA + mB, den3 = mA + mB;
    float num0 = mA * vA.x + mB * vB.x;
    float num1 = mA * vA.y + mB * vB.y;
    float num2 = mA * vA.z + mB * vB.z;
    float num3 = mA * vA.w + mB * vB.w;

    if (i >= S_ - 1 && i <= L_ - S_) {
        // Interior rows: every tap w=1..63 is in-sequence; branch-free body,
        // j = i-S+w always in [0, L-1] here so the global V address is valid.
#pragma unroll 7
        for (int w = 1; w < 2 * S_; ++w) {
            const int r = rr + w;                       // 1..94, always staged
            const float4 kk = *(const float4*)&Kw[r][cq];
            const float4 pp = *(const float4*)&Pw[w][cq];
            const float4 vv = *(const float4*)(Vcol + (size_t)(i - S_ + w) * E_);
            const float e0 = exp2f(qs0 * (kk.x + pp.x));
            const float e1 = exp2f(qs1 * (kk.y + pp.y));
            const float e2 = exp2f(qs2 * (kk.z + pp.z));
            const float e3 = exp2f(qs3 * (kk.w + pp.w));
            den0 += e0; den1 += e1; den2 += e2; den3 += e3;
            num0 += e0 * vv.x; num1 += e1 * vv.y;
            num2 += e2 * vv.z; num3 += e3 * vv.w;
        }
    } else {
        // Edge rows (first/last x-block only): 0/1-mask invalid positions,
        // clamp the global V address.
#pragma unroll 7
        for (int w = 1; w < 2 * S_; ++w) {
            const int r = rr + w;
            const int j = i - S_ + w;
            const int jc = j < 0 ? 0 : (j > L_ - 1 ? L_ - 1 : j);
            const float m = (j >= 0 && j <= L_ - 1) ? 1.f : 0.f;
            const float4 kk = *(const float4*)&Kw[r][cq];
            const float4 pp = *(const float4*)&Pw[w][cq];
            const float4 vv = *(const float4*)(Vcol + (size_t)jc * E_);
            const float e0 = m * exp2f(qs0 * (kk.x + pp.x));
            const float e1 = m * exp2f(qs1 * (kk.y + pp.y));
            const float e2 = m * exp2f(qs2 * (kk.z + pp.z));
            const float e3 = m * exp2f(qs3 * (kk.w + pp.w));
            den0 += e0; den1 += e1; den2 += e2; den3 += e3;
            num0 += e0 * vv.x; num1 += e1 * vv.y;
            num2 += e2 * vv.z; num3 += e3 * vv.w;
        }
    }

    const float s0 = 1.f / (1.f + __expf(-qv.x));
    const float s1 = 1.f / (1.f + __expf(-qv.y));
    const float s2 = 1.f / (1.f + __expf(-qv.z));
    const float s3 = 1.f / (1.f + __expf(-qv.w));

    float4 o;
    o.x = s0 * s0 * num0 / den0;
    o.y = s1 * s1 * num1 / den1;
    o.z = s2 * s2 * num2 / den2;
    o.w = s3 * s3 * num3 / den3;
    *(float4*)(out + ((size_t)b * L_ + i) * E_ + c0 + cq) = o;
}

// ===========================================================================
// PATH B (ws too small; fallback only): fully fused, fp32.
// ===========================================================================
#define TI 32
#define CG 64
#define RK 96
#define LDP 68

__global__ __launch_bounds__(256) void aft_fused(
    const float* __restrict__ q,
    const float* __restrict__ Wq, const float* __restrict__ bq,
    const float* __restrict__ Wk, const float* __restrict__ bk,
    const float* __restrict__ Wv, const float* __restrict__ bv,
    const float* __restrict__ pb,
    float* __restrict__ out)
{
    __shared__ float Kl[RK][LDP];
    __shared__ float Vl[RK][LDP];
    __shared__ float Ql[TI][LDP];

    const int i0 = blockIdx.x * TI;
    const int b  = blockIdx.y;
    const int c0 = blockIdx.z * CG;

    const int wave = threadIdx.x >> 6;
    const int lane = threadIdx.x & 63;
    const int rsel = lane & 15;
    const int koff = (lane >> 4) * 8;

    const float* qb = q + (size_t)b * L_ * E_;

    for (int job = wave; job < 56; job += 4) {
        int p, rt, ct;
        if (job < 24)      { p = 0; rt = job >> 2;        ct = job & 3; }
        else if (job < 48) { p = 1; rt = (job - 24) >> 2; ct = (job - 24) & 3; }
        else               { p = 2; rt = (job - 48) >> 2; ct = (job - 48) & 3; }

        int jrow = (p == 2) ? (i0 + rt * 16 + rsel)
                            : (i0 - S_ + rt * 16 + rsel);
        int jc = jrow < 0 ? 0 : (jrow > L_ - 1 ? L_ - 1 : jrow);
        const float* pa = qb + (size_t)jc * E_ + koff;

        const float* Wm = (p == 0) ? Wk : (p == 1) ? Wv : Wq;
        const float* bm = (p == 0) ? bk : (p == 1) ? bv : bq;
        const int n = c0 + ct * 16 + rsel;
        const float* pw = Wm + (size_t)n * E_ + koff;

        f32x4 acc = {0.f, 0.f, 0.f, 0.f};
#pragma unroll
        for (int k0 = 0; k0 < 256; k0 += 32) {
            bf16x8 ah, al, bh, bl;
            load8split(pa + k0, ah, al);
            load8split(pw + k0, bh, bl);
            acc = __builtin_amdgcn_mfma_f32_16x16x32_bf16(ah, bh, acc, 0, 0, 0);
            acc = __builtin_amdgcn_mfma_f32_16x16x32_bf16(ah, bl, acc, 0, 0, 0);
            acc = __builtin_amdgcn_mfma_f32_16x16x32_bf16(al, bh, acc, 0, 0, 0);
        }

        const float bias = bm[n];
        const int row0 = rt * 16 + (lane >> 4) * 4;
        const int colc = ct * 16 + rsel;
        float* dst = (p == 0) ? &Kl[0][0] : (p == 1) ? &Vl[0][0] : &Ql[0][0];
#pragma unroll
        for (int r = 0; r < 4; ++r)
            dst[(size_t)(row0 + r) * LDP + colc] = acc[r] + bias;
    }
    __syncthreads();

    const int cq  = threadIdx.x & 15;
    const int is0 = threadIdx.x >> 4;
    const int cL  = cq * 4;
    const int cG  = c0 + cL;
    const float* pbc = pb + cG;

    for (int rr = is0; rr < TI; rr += 16) {
        const int i = i0 + rr;
        const float4 qv = *(const float4*)&Ql[rr][cL];

        float den0 = 0.f, den1 = 0.f, den2 = 0.f, den3 = 0.f;
        float num0 = 0.f, num1 = 0.f, num2 = 0.f, num3 = 0.f;

        const int jlo = (i - S_ < 0) ? 0 : (i - S_);
        const int jhi = (i + S_ > L_ - 1) ? (L_ - 1) : (i + S_);

        for (int j = jlo; j <= jhi; ++j) {
            const int r = j - (i0 - S_);
            const int w = j - i + S_;
            const float4 vv = *(const float4*)&Vl[r][cL];

            float kx = 0.f, ky = 0.f, kz = 0.f, kw = 0.f;
            if (w != 0 && w != 2 * S_) {
                const float4 kk = *(const float4*)&Kl[r][cL];
                const float4 pp = *(const float4*)(pbc + (size_t)w * E_);
                kx = kk.x + pp.x;
                ky = kk.y + pp.y;
                kz = kk.z + pp.z;
                kw = kk.w + pp.w;
            }
            const float e0 = __expf(qv.x * kx);
            const float e1 = __expf(qv.y * ky);
            const float e2 = __expf(qv.z * kz);
            const float e3 = __expf(qv.w * kw);
            den0 += e0; den1 += e1; den2 += e2; den3 += e3;
            num0 += e0 * vv.x; num1 += e1 * vv.y;
            num2 += e2 * vv.z; num3 += e3 * vv.w;
        }

        const float s0 = 1.f / (1.f + __expf(-qv.x));
        const float s1 = 1.f / (1.f + __expf(-qv.y));
        const float s2 = 1.f / (1.f + __expf(-qv.z));
        const float s3 = 1.f / (1.f + __expf(-qv.w));

        float4 o;
        o.x = s0 * s0 * num0 / den0;
        o.y = s1 * s1 * num1 / den1;
        o.z = s2 * s2 * num2 / den2;
        o.w = s3 * s3 * num3 / den3;
        *(float4*)(out + ((size_t)b * L_ + i) * E_ + cG) = o;
    }
}

extern "C" void kernel_launch(void* const* d_in, const int* in_sizes, int n_in,
                              void* d_out, int out_size, void* d_ws, size_t ws_size,
                              hipStream_t stream) {
    const float* q  = (const float*)d_in[0];
    const float* Wq = (const float*)d_in[1];
    const float* bq = (const float*)d_in[2];
    const float* Wk = (const float*)d_in[3];
    const float* bk = (const float*)d_in[4];
    const float* Wv = (const float*)d_in[5];
    const float* bv = (const float*)d_in[6];
    const float* pb = (const float*)d_in[7];

    const size_t needA = (size_t)3 * 4096 * 256 * sizeof(float);  // 12.6 MB

    if (ws_size >= needA) {
        float* Qf = (float*)d_ws;
        float* Kf = Qf + (size_t)4096 * 256;
        float* Vf = Kf + (size_t)4096 * 256;
        qkv_gemm2<<<dim3(128, 1, 3), 256, 0, stream>>>(q, Wq, bq, Wk, bk, Wv, bv,
                                                       Qf, Kf, Vf);
        aft_stage2d<<<dim3(L_ / TI3, B_, E_ / CH3), 256, 0, stream>>>(
            Qf, Kf, Vf, pb, (float*)d_out);
    } else {
        aft_fused<<<dim3(L_ / TI, B_, E_ / CG), 256, 0, stream>>>(
            q, Wq, bq, Wk, bk, Wv, bv, pb, (float*)d_out);
    }
}

// Round 3
// 122.398 us; speedup vs baseline: 1.1394x; 1.1394x over previous
//
#include <hip/hip_runtime.h>
#include <hip/hip_bf16.h>

#define B_ 4
#define L_ 1024
#define E_ 256
#define S_ 32

typedef __bf16 bf16x8 __attribute__((ext_vector_type(8)));
typedef float f32x4 __attribute__((ext_vector_type(4)));

__device__ __forceinline__ __bf16 bf_from_bits(unsigned short u) {
    __bf16 b;
    __builtin_memcpy(&b, &u, 2);
    return b;
}

// Split fp32 -> bf16 hi (truncate) + bf16 lo (residual). a ~= hi + lo with
// ~2^-17 rel error when both terms are used in the MFMA product expansion.
__device__ __forceinline__ void load8split(const float* __restrict__ p,
                                           bf16x8& h, bf16x8& l) {
    const float4 x0 = *(const float4*)p;
    const float4 x1 = *(const float4*)(p + 4);
    const float xs[8] = {x0.x, x0.y, x0.z, x0.w, x1.x, x1.y, x1.z, x1.w};
#pragma unroll
    for (int j = 0; j < 8; ++j) {
        const unsigned hb = __float_as_uint(xs[j]) & 0xFFFF0000u;
        h[j] = bf_from_bits((unsigned short)(hb >> 16));
        l[j] = (__bf16)(xs[j] - __uint_as_float(hb));
    }
}

// ===========================================================================
// PATH A kernel 1: Q/K/V projections, out[m,n] = sum_k A[m,k]*W[n,k] + b[n].
// Block 256 = 4 waves; block slab = 32 rows x 256 cols (one matrix, z-dim).
// Wave: 2 M-tiles x 4 N-tiles (8 accumulators) -> 24 MFMA per 6 fragment
// loads per K-step. (~5 us; unchanged — not the bottleneck.)
// ===========================================================================
__global__ __launch_bounds__(256, 1) void qkv_gemm2(
    const float* __restrict__ A,
    const float* __restrict__ Wq, const float* __restrict__ bq,
    const float* __restrict__ Wk, const float* __restrict__ bk,
    const float* __restrict__ Wv, const float* __restrict__ bv,
    float* __restrict__ Qo, float* __restrict__ Ko, float* __restrict__ Vo)
{
    const float* Wm;
    const float* bm;
    float* Om;
    const int z = blockIdx.z;
    if (z == 0)      { Wm = Wq; bm = bq; Om = Qo; }
    else if (z == 1) { Wm = Wk; bm = bk; Om = Ko; }
    else             { Wm = Wv; bm = bv; Om = Vo; }

    const int wave = threadIdx.x >> 6;
    const int lane = threadIdx.x & 63;
    const int rsel = lane & 15;
    const int koff = (lane >> 4) * 8;

    const int m0 = blockIdx.x * 32;
    const int nb = wave * 64;

    const float* pa0 = A + (size_t)(m0 + rsel) * 256 + koff;
    const float* pa1 = pa0 + (size_t)16 * 256;
    const float* pw0 = Wm + (size_t)(nb + 0  + rsel) * 256 + koff;
    const float* pw1 = Wm + (size_t)(nb + 16 + rsel) * 256 + koff;
    const float* pw2 = Wm + (size_t)(nb + 32 + rsel) * 256 + koff;
    const float* pw3 = Wm + (size_t)(nb + 48 + rsel) * 256 + koff;

    f32x4 acc[2][4];
#pragma unroll
    for (int mt = 0; mt < 2; ++mt)
#pragma unroll
        for (int nt = 0; nt < 4; ++nt)
            acc[mt][nt] = (f32x4){0.f, 0.f, 0.f, 0.f};

#pragma unroll
    for (int k0 = 0; k0 < 256; k0 += 32) {
        bf16x8 ah[2], al[2], bh[4], bl[4];
        load8split(pa0 + k0, ah[0], al[0]);
        load8split(pa1 + k0, ah[1], al[1]);
        load8split(pw0 + k0, bh[0], bl[0]);
        load8split(pw1 + k0, bh[1], bl[1]);
        load8split(pw2 + k0, bh[2], bl[2]);
        load8split(pw3 + k0, bh[3], bl[3]);
#pragma unroll
        for (int mt = 0; mt < 2; ++mt)
#pragma unroll
            for (int nt = 0; nt < 4; ++nt) {
                acc[mt][nt] = __builtin_amdgcn_mfma_f32_16x16x32_bf16(
                    ah[mt], bh[nt], acc[mt][nt], 0, 0, 0);
                acc[mt][nt] = __builtin_amdgcn_mfma_f32_16x16x32_bf16(
                    ah[mt], bl[nt], acc[mt][nt], 0, 0, 0);
                acc[mt][nt] = __builtin_amdgcn_mfma_f32_16x16x32_bf16(
                    al[mt], bh[nt], acc[mt][nt], 0, 0, 0);
            }
    }

#pragma unroll
    for (int mt = 0; mt < 2; ++mt) {
        const int mrow = m0 + mt * 16 + (lane >> 4) * 4;
#pragma unroll
        for (int nt = 0; nt < 4; ++nt) {
            const int n = nb + nt * 16 + rsel;
            const float bias = bm[n];
#pragma unroll
            for (int r = 0; r < 4; ++r)
                Om[(size_t)(mrow + r) * 256 + n] = acc[mt][nt][r] + bias;
        }
    }
}

// ===========================================================================
// PATH A kernel 2 (v5): windowed per-channel softmax + context + sigmoid^2.
// v3 was DS-pipe-bound: 16 waves/CU x 63 taps x 3 ds_read_b128 (12cy) ~ 15us
// on the per-CU DS pipe (VALU/trans only ~3.4us each per SIMD). v4 (V via
// VMEM) was worse: compiler didn't pipeline the scattered loads (VGPR=36),
// latency-bound at 47us. Fix here: 2-ROW PAIRING —
//  - Each thread owns rows i,i+1 and walks absolute j once: K[j],V[j] from
//    LDS serve BOTH rows (row i tap w, row i+1 tap w-1); row i+1's pos_bias
//    P[w-1] is last step's P[w] (rolling register). DS: 3 reads / 2 row-taps.
//  - 2 channels/thread (float2, ds_read_b64 ~6cy) keeps total waves at 4096
//    => 4 waves/SIMD latency hiding, grid 1024 blocks = 4/CU.
//  - DS time model: 16w x 64steps x 3 b64 x 6cy = 18.4k cy/CU ~ 7.7us.
//  - Pw reads are wave-uniform per step (broadcast, conflict-free).
//  - w=0 / w=2S strict-mask taps peeled (e = valid?1:0) as before.
// ===========================================================================
#define TI5 32          // i-rows per block (16 pairs)
#define CH5 32          // channels per block
#define HR5 96          // staged rows: j in [i0-S, i0+TI5-1+S]
#define PS5 36          // padded LDS stride (floats)

__global__ __launch_bounds__(256, 4) void aft_stage2e(
    const float* __restrict__ Q, const float* __restrict__ K,
    const float* __restrict__ V, const float* __restrict__ pb,
    float* __restrict__ out)
{
    __shared__ float Kw[HR5][PS5];        // 13824 B
    __shared__ float Vw[HR5][PS5];        // 13824 B
    __shared__ float Pw[2 * S_ + 1][PS5]; //  9360 B (total 37008 B, 4 blk/CU)

    const int tid = threadIdx.x;
    const int b  = blockIdx.y;
    const int i0 = blockIdx.x * TI5;
    const int c0 = blockIdx.z * CH5;

    const int duo = tid & 15;       // channel duo 0..15 -> 2 floats
    const int pr  = tid >> 4;       // row pair 0..15
    const int c   = duo * 2;
    const int iA  = i0 + pr * 2;
    const int iB  = iA + 1;
    const int rb  = pr * 2;         // LDS row of j = iA - S

    // Q reads issued before staging; complete under the barrier.
    const float2 qA = *(const float2*)(Q + ((size_t)b * L_ + iA) * E_ + c0 + c);
    const float2 qB = *(const float2*)(Q + ((size_t)b * L_ + iB) * E_ + c0 + c);

    const float* Kb = K + (size_t)b * L_ * E_;
    const float* Vb = V + (size_t)b * L_ * E_;

    // ---- stage K/V halo rows (96 rows x 32 ch) ----
    for (int idx = tid; idx < HR5 * 8; idx += 256) {
        const int r = idx >> 3;
        const int cc = (idx & 7) * 4;
        int j = i0 - S_ + r;
        j = j < 0 ? 0 : (j > L_ - 1 ? L_ - 1 : j);   // clamped rows are masked
        const size_t g = (size_t)j * E_ + c0 + cc;
        *(float4*)&Kw[r][cc] = *(const float4*)(Kb + g);
        *(float4*)&Vw[r][cc] = *(const float4*)(Vb + g);
    }
    // ---- stage pos_bias slice (65 rows x 32 ch) ----
    for (int idx = tid; idx < (2 * S_ + 1) * 8; idx += 256) {
        const int r = idx >> 3;
        const int cc = (idx & 7) * 4;
        *(float4*)&Pw[r][cc] = *(const float4*)(pb + (size_t)r * E_ + c0 + cc);
    }
    __syncthreads();

    const float LOG2E = 1.44269504088896340736f;
    const float qsA0 = qA.x * LOG2E, qsA1 = qA.y * LOG2E;
    const float qsB0 = qB.x * LOG2E, qsB1 = qB.y * LOG2E;

    float dA0, dA1, nA0, nA1, dB0, dB1, nB0, nB1;

    // Outer peel: row A w=0 (j=iA-S, r=rb) — strict mask zeroes K -> e=valid.
    {
        const float m = (iA >= S_) ? 1.f : 0.f;
        const float2 vv = *(const float2*)&Vw[rb][c];
        dA0 = m; dA1 = m; nA0 = m * vv.x; nA1 = m * vv.y;
    }
    // Outer peel: row B w=2S (j=iB+S, r=rb+65).
    {
        const float m = (iB <= L_ - 1 - S_) ? 1.f : 0.f;
        const float2 vv = *(const float2*)&Vw[rb + 65][c];
        dB0 = m; dB1 = m; nB0 = m * vv.x; nB1 = m * vv.y;
    }

    float2 ppRoll;  // Pw[t+1] of the previous step == Pw[w'] for row B

    const bool interior = (blockIdx.x >= 1) && (blockIdx.x <= (L_ / TI5) - 2);

    if (interior) {
        // t = 0: j = iA-S+1 (valid). A: regular w=1. B: peel w'=0 (e=1).
        {
            const int r = rb + 1;
            const float2 kk = *(const float2*)&Kw[r][c];
            const float2 pp = *(const float2*)&Pw[1][c];
            const float2 vv = *(const float2*)&Vw[r][c];
            const float a0 = exp2f(qsA0 * (kk.x + pp.x));
            const float a1 = exp2f(qsA1 * (kk.y + pp.y));
            dA0 += a0; nA0 += a0 * vv.x; dA1 += a1; nA1 += a1 * vv.y;
            dB0 += 1.f; nB0 += vv.x;     dB1 += 1.f; nB1 += vv.y;
            ppRoll = pp;
        }
        // t = 1..62: both rows regular. K/V shared; P rolls for row B.
#pragma unroll 8
        for (int t = 1; t <= 62; ++t) {
            const int r = rb + 1 + t;
            const float2 kk = *(const float2*)&Kw[r][c];
            const float2 pp = *(const float2*)&Pw[t + 1][c];
            const float2 vv = *(const float2*)&Vw[r][c];
            const float a0 = exp2f(qsA0 * (kk.x + pp.x));
            const float a1 = exp2f(qsA1 * (kk.y + pp.y));
            const float b0 = exp2f(qsB0 * (kk.x + ppRoll.x));
            const float b1 = exp2f(qsB1 * (kk.y + ppRoll.y));
            dA0 += a0; nA0 += a0 * vv.x; dA1 += a1; nA1 += a1 * vv.y;
            dB0 += b0; nB0 += b0 * vv.x; dB1 += b1; nB1 += b1 * vv.y;
            ppRoll = pp;
        }
        // t = 63: j = iA+S. A: peel w=2S (e=1). B: regular w'=63 (ppRoll=Pw[63]).
        {
            const int r = rb + 64;
            const float2 kk = *(const float2*)&Kw[r][c];
            const float2 vv = *(const float2*)&Vw[r][c];
            const float b0 = exp2f(qsB0 * (kk.x + ppRoll.x));
            const float b1 = exp2f(qsB1 * (kk.y + ppRoll.y));
            dB0 += b0; nB0 += b0 * vv.x; dB1 += b1; nB1 += b1 * vv.y;
            dA0 += 1.f; nA0 += vv.x;     dA1 += 1.f; nA1 += vv.y;
        }
    } else {
        // Edge blocks (x = 0 or last): mask every step by j-validity.
        {
            const int j = iA - S_ + 1;
            const float m = (j >= 0 && j <= L_ - 1) ? 1.f : 0.f;
            const int r = rb + 1;
            const float2 kk = *(const float2*)&Kw[r][c];
            const float2 pp = *(const float2*)&Pw[1][c];
            const float2 vv = *(const float2*)&Vw[r][c];
            const float a0 = m * exp2f(qsA0 * (kk.x + pp.x));
            const float a1 = m * exp2f(qsA1 * (kk.y + pp.y));
            dA0 += a0; nA0 += a0 * vv.x; dA1 += a1; nA1 += a1 * vv.y;
            dB0 += m;  nB0 += m * vv.x;  dB1 += m;  nB1 += m * vv.y;
            ppRoll = pp;
        }
#pragma unroll 8
        for (int t = 1; t <= 62; ++t) {
            const int j = iA - S_ + 1 + t;
            const float m = (j >= 0 && j <= L_ - 1) ? 1.f : 0.f;
            const int r = rb + 1 + t;
            const float2 kk = *(const float2*)&Kw[r][c];
            const float2 pp = *(const float2*)&Pw[t + 1][c];
            const float2 vv = *(const float2*)&Vw[r][c];
            const float a0 = m * exp2f(qsA0 * (kk.x + pp.x));
            const float a1 = m * exp2f(qsA1 * (kk.y + pp.y));
            const float b0 = m * exp2f(qsB0 * (kk.x + ppRoll.x));
            const float b1 = m * exp2f(qsB1 * (kk.y + ppRoll.y));
            dA0 += a0; nA0 += a0 * vv.x; dA1 += a1; nA1 += a1 * vv.y;
            dB0 += b0; nB0 += b0 * vv.x; dB1 += b1; nB1 += b1 * vv.y;
            ppRoll = pp;
        }
        {
            const int j = iA + S_;
            const float m = (j >= 0 && j <= L_ - 1) ? 1.f : 0.f;
            const int r = rb + 64;
            const float2 kk = *(const float2*)&Kw[r][c];
            const float2 vv = *(const float2*)&Vw[r][c];
            const float b0 = m * exp2f(qsB0 * (kk.x + ppRoll.x));
            const float b1 = m * exp2f(qsB1 * (kk.y + ppRoll.y));
            dB0 += b0; nB0 += b0 * vv.x; dB1 += b1; nB1 += b1 * vv.y;
            dA0 += m;  nA0 += m * vv.x;  dA1 += m;  nA1 += m * vv.y;
        }
    }

    // sigmoid via exp2 (reuse qs = q*log2e): sig = 1/(1+2^-qs)
    const float sA0 = 1.f / (1.f + exp2f(-qsA0));
    const float sA1 = 1.f / (1.f + exp2f(-qsA1));
    const float sB0 = 1.f / (1.f + exp2f(-qsB0));
    const float sB1 = 1.f / (1.f + exp2f(-qsB1));

    float2 oA, oB;
    oA.x = sA0 * sA0 * nA0 / dA0;
    oA.y = sA1 * sA1 * nA1 / dA1;
    oB.x = sB0 * sB0 * nB0 / dB0;
    oB.y = sB1 * sB1 * nB1 / dB1;
    *(float2*)(out + ((size_t)b * L_ + iA) * E_ + c0 + c) = oA;
    *(float2*)(out + ((size_t)b * L_ + iB) * E_ + c0 + c) = oB;
}

// ===========================================================================
// PATH B (ws too small; fallback only): fully fused, fp32.
// ===========================================================================
#define TI 32
#define CG 64
#define RK 96
#define LDP 68

__global__ __launch_bounds__(256) void aft_fused(
    const float* __restrict__ q,
    const float* __restrict__ Wq, const float* __restrict__ bq,
    const float* __restrict__ Wk, const float* __restrict__ bk,
    const float* __restrict__ Wv, const float* __restrict__ bv,
    const float* __restrict__ pb,
    float* __restrict__ out)
{
    __shared__ float Kl[RK][LDP];
    __shared__ float Vl[RK][LDP];
    __shared__ float Ql[TI][LDP];

    const int i0 = blockIdx.x * TI;
    const int b  = blockIdx.y;
    const int c0 = blockIdx.z * CG;

    const int wave = threadIdx.x >> 6;
    const int lane = threadIdx.x & 63;
    const int rsel = lane & 15;
    const int koff = (lane >> 4) * 8;

    const float* qb = q + (size_t)b * L_ * E_;

    for (int job = wave; job < 56; job += 4) {
        int p, rt, ct;
        if (job < 24)      { p = 0; rt = job >> 2;        ct = job & 3; }
        else if (job < 48) { p = 1; rt = (job - 24) >> 2; ct = (job - 24) & 3; }
        else               { p = 2; rt = (job - 48) >> 2; ct = (job - 48) & 3; }

        int jrow = (p == 2) ? (i0 + rt * 16 + rsel)
                            : (i0 - S_ + rt * 16 + rsel);
        int jc = jrow < 0 ? 0 : (jrow > L_ - 1 ? L_ - 1 : jrow);
        const float* pa = qb + (size_t)jc * E_ + koff;

        const float* Wm = (p == 0) ? Wk : (p == 1) ? Wv : Wq;
        const float* bm = (p == 0) ? bk : (p == 1) ? bv : bq;
        const int n = c0 + ct * 16 + rsel;
        const float* pw = Wm + (size_t)n * E_ + koff;

        f32x4 acc = {0.f, 0.f, 0.f, 0.f};
#pragma unroll
        for (int k0 = 0; k0 < 256; k0 += 32) {
            bf16x8 ah, al, bh, bl;
            load8split(pa + k0, ah, al);
            load8split(pw + k0, bh, bl);
            acc = __builtin_amdgcn_mfma_f32_16x16x32_bf16(ah, bh, acc, 0, 0, 0);
            acc = __builtin_amdgcn_mfma_f32_16x16x32_bf16(ah, bl, acc, 0, 0, 0);
            acc = __builtin_amdgcn_mfma_f32_16x16x32_bf16(al, bh, acc, 0, 0, 0);
        }

        const float bias = bm[n];
        const int row0 = rt * 16 + (lane >> 4) * 4;
        const int colc = ct * 16 + rsel;
        float* dst = (p == 0) ? &Kl[0][0] : (p == 1) ? &Vl[0][0] : &Ql[0][0];
#pragma unroll
        for (int r = 0; r < 4; ++r)
            dst[(size_t)(row0 + r) * LDP + colc] = acc[r] + bias;
    }
    __syncthreads();

    const int cq  = threadIdx.x & 15;
    const int is0 = threadIdx.x >> 4;
    const int cL  = cq * 4;
    const int cG  = c0 + cL;
    const float* pbc = pb + cG;

    for (int rr = is0; rr < TI; rr += 16) {
        const int i = i0 + rr;
        const float4 qv = *(const float4*)&Ql[rr][cL];

        float den0 = 0.f, den1 = 0.f, den2 = 0.f, den3 = 0.f;
        float num0 = 0.f, num1 = 0.f, num2 = 0.f, num3 = 0.f;

        const int jlo = (i - S_ < 0) ? 0 : (i - S_);
        const int jhi = (i + S_ > L_ - 1) ? (L_ - 1) : (i + S_);

        for (int j = jlo; j <= jhi; ++j) {
            const int r = j - (i0 - S_);
            const int w = j - i + S_;
            const float4 vv = *(const float4*)&Vl[r][cL];

            float kx = 0.f, ky = 0.f, kz = 0.f, kw = 0.f;
            if (w != 0 && w != 2 * S_) {
                const float4 kk = *(const float4*)&Kl[r][cL];
                const float4 pp = *(const float4*)(pbc + (size_t)w * E_);
                kx = kk.x + pp.x;
                ky = kk.y + pp.y;
                kz = kk.z + pp.z;
                kw = kk.w + pp.w;
            }
            const float e0 = __expf(qv.x * kx);
            const float e1 = __expf(qv.y * ky);
            const float e2 = __expf(qv.z * kz);
            const float e3 = __expf(qv.w * kw);
            den0 += e0; den1 += e1; den2 += e2; den3 += e3;
            num0 += e0 * vv.x; num1 += e1 * vv.y;
            num2 += e2 * vv.z; num3 += e3 * vv.w;
        }

        const float s0 = 1.f / (1.f + __expf(-qv.x));
        const float s1 = 1.f / (1.f + __expf(-qv.y));
        const float s2 = 1.f / (1.f + __expf(-qv.z));
        const float s3 = 1.f / (1.f + __expf(-qv.w));

        float4 o;
        o.x = s0 * s0 * num0 / den0;
        o.y = s1 * s1 * num1 / den1;
        o.z = s2 * s2 * num2 / den2;
        o.w = s3 * s3 * num3 / den3;
        *(float4*)(out + ((size_t)b * L_ + i) * E_ + cG) = o;
    }
}

extern "C" void kernel_launch(void* const* d_in, const int* in_sizes, int n_in,
                              void* d_out, int out_size, void* d_ws, size_t ws_size,
                              hipStream_t stream) {
    const float* q  = (const float*)d_in[0];
    const float* Wq = (const float*)d_in[1];
    const float* bq = (const float*)d_in[2];
    const float* Wk = (const float*)d_in[3];
    const float* bk = (const float*)d_in[4];
    const float* Wv = (const float*)d_in[5];
    const float* bv = (const float*)d_in[6];
    const float* pb = (const float*)d_in[7];

    const size_t needA = (size_t)3 * 4096 * 256 * sizeof(float);  // 12.6 MB

    if (ws_size >= needA) {
        float* Qf = (float*)d_ws;
        float* Kf = Qf + (size_t)4096 * 256;
        float* Vf = Kf + (size_t)4096 * 256;
        qkv_gemm2<<<dim3(128, 1, 3), 256, 0, stream>>>(q, Wq, bq, Wk, bk, Wv, bv,
                                                       Qf, Kf, Vf);
        aft_stage2e<<<dim3(L_ / TI5, B_, E_ / CH5), 256, 0, stream>>>(
            Qf, Kf, Vf, pb, (float*)d_out);
    } else {
        aft_fused<<<dim3(L_ / TI, B_, E_ / CG), 256, 0, stream>>>(
            q, Wq, bq, Wk, bk, Wv, bv, pb, (float*)d_out);
    }
}

// Round 4
// 115.091 us; speedup vs baseline: 1.2118x; 1.0635x over previous
//
#include <hip/hip_runtime.h>
#include <hip/hip_bf16.h>

#define B_ 4
#define L_ 1024
#define E_ 256
#define S_ 32

typedef __bf16 bf16x8 __attribute__((ext_vector_type(8)));
typedef float f32x4 __attribute__((ext_vector_type(4)));

__device__ __forceinline__ __bf16 bf_from_bits(unsigned short u) {
    __bf16 b;
    __builtin_memcpy(&b, &u, 2);
    return b;
}

// Raw v_exp_f32 (2^x). The libm exp2f goes through the OCML denormal-correct
// wrapper (~5 VALU of cmp/scale fixup per call) because hipcc keeps denormals
// on; softmax terms that would be denormal are ~0 anyway, so raw is safe.
__device__ __forceinline__ float fexp2(float x) {
#if __has_builtin(__builtin_amdgcn_exp2f)
    return __builtin_amdgcn_exp2f(x);
#else
    return exp2f(x);
#endif
}

// Split fp32 -> bf16 hi (truncate) + bf16 lo (residual). a ~= hi + lo with
// ~2^-17 rel error when both terms are used in the MFMA product expansion.
__device__ __forceinline__ void load8split(const float* __restrict__ p,
                                           bf16x8& h, bf16x8& l) {
    const float4 x0 = *(const float4*)p;
    const float4 x1 = *(const float4*)(p + 4);
    const float xs[8] = {x0.x, x0.y, x0.z, x0.w, x1.x, x1.y, x1.z, x1.w};
#pragma unroll
    for (int j = 0; j < 8; ++j) {
        const unsigned hb = __float_as_uint(xs[j]) & 0xFFFF0000u;
        h[j] = bf_from_bits((unsigned short)(hb >> 16));
        l[j] = (__bf16)(xs[j] - __uint_as_float(hb));
    }
}

// ===========================================================================
// PATH A kernel 1: Q/K/V projections, out[m,n] = sum_k A[m,k]*W[n,k] + b[n].
// Block 256 = 4 waves; block slab = 32 rows x 256 cols (one matrix, z-dim).
// Wave: 2 M-tiles x 4 N-tiles (8 accumulators) -> 24 MFMA per 6 fragment
// loads per K-step. (~5 us; unchanged — not the bottleneck.)
// ===========================================================================
__global__ __launch_bounds__(256, 1) void qkv_gemm2(
    const float* __restrict__ A,
    const float* __restrict__ Wq, const float* __restrict__ bq,
    const float* __restrict__ Wk, const float* __restrict__ bk,
    const float* __restrict__ Wv, const float* __restrict__ bv,
    float* __restrict__ Qo, float* __restrict__ Ko, float* __restrict__ Vo)
{
    const float* Wm;
    const float* bm;
    float* Om;
    const int z = blockIdx.z;
    if (z == 0)      { Wm = Wq; bm = bq; Om = Qo; }
    else if (z == 1) { Wm = Wk; bm = bk; Om = Ko; }
    else             { Wm = Wv; bm = bv; Om = Vo; }

    const int wave = threadIdx.x >> 6;
    const int lane = threadIdx.x & 63;
    const int rsel = lane & 15;
    const int koff = (lane >> 4) * 8;

    const int m0 = blockIdx.x * 32;
    const int nb = wave * 64;

    const float* pa0 = A + (size_t)(m0 + rsel) * 256 + koff;
    const float* pa1 = pa0 + (size_t)16 * 256;
    const float* pw0 = Wm + (size_t)(nb + 0  + rsel) * 256 + koff;
    const float* pw1 = Wm + (size_t)(nb + 16 + rsel) * 256 + koff;
    const float* pw2 = Wm + (size_t)(nb + 32 + rsel) * 256 + koff;
    const float* pw3 = Wm + (size_t)(nb + 48 + rsel) * 256 + koff;

    f32x4 acc[2][4];
#pragma unroll
    for (int mt = 0; mt < 2; ++mt)
#pragma unroll
        for (int nt = 0; nt < 4; ++nt)
            acc[mt][nt] = (f32x4){0.f, 0.f, 0.f, 0.f};

#pragma unroll
    for (int k0 = 0; k0 < 256; k0 += 32) {
        bf16x8 ah[2], al[2], bh[4], bl[4];
        load8split(pa0 + k0, ah[0], al[0]);
        load8split(pa1 + k0, ah[1], al[1]);
        load8split(pw0 + k0, bh[0], bl[0]);
        load8split(pw1 + k0, bh[1], bl[1]);
        load8split(pw2 + k0, bh[2], bl[2]);
        load8split(pw3 + k0, bh[3], bl[3]);
#pragma unroll
        for (int mt = 0; mt < 2; ++mt)
#pragma unroll
            for (int nt = 0; nt < 4; ++nt) {
                acc[mt][nt] = __builtin_amdgcn_mfma_f32_16x16x32_bf16(
                    ah[mt], bh[nt], acc[mt][nt], 0, 0, 0);
                acc[mt][nt] = __builtin_amdgcn_mfma_f32_16x16x32_bf16(
                    ah[mt], bl[nt], acc[mt][nt], 0, 0, 0);
                acc[mt][nt] = __builtin_amdgcn_mfma_f32_16x16x32_bf16(
                    al[mt], bh[nt], acc[mt][nt], 0, 0, 0);
            }
    }

#pragma unroll
    for (int mt = 0; mt < 2; ++mt) {
        const int mrow = m0 + mt * 16 + (lane >> 4) * 4;
#pragma unroll
        for (int nt = 0; nt < 4; ++nt) {
            const int n = nb + nt * 16 + rsel;
            const float bias = bm[n];
#pragma unroll
            for (int r = 0; r < 4; ++r)
                Om[(size_t)(mrow + r) * 256 + n] = acc[mt][nt][r] + bias;
        }
    }
}

// ===========================================================================
// PATH A kernel 2 (v6): windowed per-channel softmax + context + sigmoid^2.
// Structure = v5 (2-row pairing: thread owns rows i,i+1; K[j]/V[j] LDS reads
// serve both rows; pos_bias rolls in a register; 2 channels/thread, b64
// reads; 4 blocks/CU x 4 waves). Single change vs v5: ALL exp2f -> raw
// v_exp_f32 via __builtin_amdgcn_exp2f. exp2f was lowering to the OCML
// denormal-correct wrapper (~5 VALU fixup/call = +20 VALU/step), which made
// stage-2 VALU-issue-bound and masked v5's DS savings (v4's measured
// VALUBusy 39% = 18.5us of issue was ~3-4x the hand-counted budget).
// Interior step is now 16 VALU + 4 trans + 3 ds_read_b64.
// ===========================================================================
#define TI5 32          // i-rows per block (16 pairs)
#define CH5 32          // channels per block
#define HR5 96          // staged rows: j in [i0-S, i0+TI5-1+S]
#define PS5 36          // padded LDS stride (floats)

__global__ __launch_bounds__(256, 4) void aft_stage2f(
    const float* __restrict__ Q, const float* __restrict__ K,
    const float* __restrict__ V, const float* __restrict__ pb,
    float* __restrict__ out)
{
    __shared__ float Kw[HR5][PS5];        // 13824 B
    __shared__ float Vw[HR5][PS5];        // 13824 B
    __shared__ float Pw[2 * S_ + 1][PS5]; //  9360 B (total 37008 B, 4 blk/CU)

    const int tid = threadIdx.x;
    const int b  = blockIdx.y;
    const int i0 = blockIdx.x * TI5;
    const int c0 = blockIdx.z * CH5;

    const int duo = tid & 15;       // channel duo 0..15 -> 2 floats
    const int pr  = tid >> 4;       // row pair 0..15
    const int c   = duo * 2;
    const int iA  = i0 + pr * 2;
    const int iB  = iA + 1;
    const int rb  = pr * 2;         // LDS row of j = iA - S

    // Q reads issued before staging; complete under the barrier.
    const float2 qA = *(const float2*)(Q + ((size_t)b * L_ + iA) * E_ + c0 + c);
    const float2 qB = *(const float2*)(Q + ((size_t)b * L_ + iB) * E_ + c0 + c);

    const float* Kb = K + (size_t)b * L_ * E_;
    const float* Vb = V + (size_t)b * L_ * E_;

    // ---- stage K/V halo rows (96 rows x 32 ch) ----
    for (int idx = tid; idx < HR5 * 8; idx += 256) {
        const int r = idx >> 3;
        const int cc = (idx & 7) * 4;
        int j = i0 - S_ + r;
        j = j < 0 ? 0 : (j > L_ - 1 ? L_ - 1 : j);   // clamped rows are masked
        const size_t g = (size_t)j * E_ + c0 + cc;
        *(float4*)&Kw[r][cc] = *(const float4*)(Kb + g);
        *(float4*)&Vw[r][cc] = *(const float4*)(Vb + g);
    }
    // ---- stage pos_bias slice (65 rows x 32 ch) ----
    for (int idx = tid; idx < (2 * S_ + 1) * 8; idx += 256) {
        const int r = idx >> 3;
        const int cc = (idx & 7) * 4;
        *(float4*)&Pw[r][cc] = *(const float4*)(pb + (size_t)r * E_ + c0 + cc);
    }
    __syncthreads();

    const float LOG2E = 1.44269504088896340736f;
    const float qsA0 = qA.x * LOG2E, qsA1 = qA.y * LOG2E;
    const float qsB0 = qB.x * LOG2E, qsB1 = qB.y * LOG2E;

    float dA0, dA1, nA0, nA1, dB0, dB1, nB0, nB1;

    // Outer peel: row A w=0 (j=iA-S, r=rb) — strict mask zeroes K -> e=valid.
    {
        const float m = (iA >= S_) ? 1.f : 0.f;
        const float2 vv = *(const float2*)&Vw[rb][c];
        dA0 = m; dA1 = m; nA0 = m * vv.x; nA1 = m * vv.y;
    }
    // Outer peel: row B w=2S (j=iB+S, r=rb+65).
    {
        const float m = (iB <= L_ - 1 - S_) ? 1.f : 0.f;
        const float2 vv = *(const float2*)&Vw[rb + 65][c];
        dB0 = m; dB1 = m; nB0 = m * vv.x; nB1 = m * vv.y;
    }

    float2 ppRoll;  // Pw[t+1] of the previous step == Pw[w'] for row B

    const bool interior = (blockIdx.x >= 1) && (blockIdx.x <= (L_ / TI5) - 2);

    if (interior) {
        // t = 0: j = iA-S+1 (valid). A: regular w=1. B: peel w'=0 (e=1).
        {
            const int r = rb + 1;
            const float2 kk = *(const float2*)&Kw[r][c];
            const float2 pp = *(const float2*)&Pw[1][c];
            const float2 vv = *(const float2*)&Vw[r][c];
            const float a0 = fexp2(qsA0 * (kk.x + pp.x));
            const float a1 = fexp2(qsA1 * (kk.y + pp.y));
            dA0 += a0; nA0 += a0 * vv.x; dA1 += a1; nA1 += a1 * vv.y;
            dB0 += 1.f; nB0 += vv.x;     dB1 += 1.f; nB1 += vv.y;
            ppRoll = pp;
        }
        // t = 1..62: both rows regular. K/V shared; P rolls for row B.
#pragma unroll 8
        for (int t = 1; t <= 62; ++t) {
            const int r = rb + 1 + t;
            const float2 kk = *(const float2*)&Kw[r][c];
            const float2 pp = *(const float2*)&Pw[t + 1][c];
            const float2 vv = *(const float2*)&Vw[r][c];
            const float a0 = fexp2(qsA0 * (kk.x + pp.x));
            const float a1 = fexp2(qsA1 * (kk.y + pp.y));
            const float b0 = fexp2(qsB0 * (kk.x + ppRoll.x));
            const float b1 = fexp2(qsB1 * (kk.y + ppRoll.y));
            dA0 += a0; nA0 += a0 * vv.x; dA1 += a1; nA1 += a1 * vv.y;
            dB0 += b0; nB0 += b0 * vv.x; dB1 += b1; nB1 += b1 * vv.y;
            ppRoll = pp;
        }
        // t = 63: j = iA+S. A: peel w=2S (e=1). B: regular w'=63 (ppRoll=Pw[63]).
        {
            const int r = rb + 64;
            const float2 kk = *(const float2*)&Kw[r][c];
            const float2 vv = *(const float2*)&Vw[r][c];
            const float b0 = fexp2(qsB0 * (kk.x + ppRoll.x));
            const float b1 = fexp2(qsB1 * (kk.y + ppRoll.y));
            dB0 += b0; nB0 += b0 * vv.x; dB1 += b1; nB1 += b1 * vv.y;
            dA0 += 1.f; nA0 += vv.x;     dA1 += 1.f; nA1 += vv.y;
        }
    } else {
        // Edge blocks (x = 0 or last): mask every step by j-validity.
        {
            const int j = iA - S_ + 1;
            const float m = (j >= 0 && j <= L_ - 1) ? 1.f : 0.f;
            const int r = rb + 1;
            const float2 kk = *(const float2*)&Kw[r][c];
            const float2 pp = *(const float2*)&Pw[1][c];
            const float2 vv = *(const float2*)&Vw[r][c];
            const float a0 = m * fexp2(qsA0 * (kk.x + pp.x));
            const float a1 = m * fexp2(qsA1 * (kk.y + pp.y));
            dA0 += a0; nA0 += a0 * vv.x; dA1 += a1; nA1 += a1 * vv.y;
            dB0 += m;  nB0 += m * vv.x;  dB1 += m;  nB1 += m * vv.y;
            ppRoll = pp;
        }
#pragma unroll 8
        for (int t = 1; t <= 62; ++t) {
            const int j = iA - S_ + 1 + t;
            const float m = (j >= 0 && j <= L_ - 1) ? 1.f : 0.f;
            const int r = rb + 1 + t;
            const float2 kk = *(const float2*)&Kw[r][c];
            const float2 pp = *(const float2*)&Pw[t + 1][c];
            const float2 vv = *(const float2*)&Vw[r][c];
            const float a0 = m * fexp2(qsA0 * (kk.x + pp.x));
            const float a1 = m * fexp2(qsA1 * (kk.y + pp.y));
            const float b0 = m * fexp2(qsB0 * (kk.x + ppRoll.x));
            const float b1 = m * fexp2(qsB1 * (kk.y + ppRoll.y));
            dA0 += a0; nA0 += a0 * vv.x; dA1 += a1; nA1 += a1 * vv.y;
            dB0 += b0; nB0 += b0 * vv.x; dB1 += b1; nB1 += b1 * vv.y;
            ppRoll = pp;
        }
        {
            const int j = iA + S_;
            const float m = (j >= 0 && j <= L_ - 1) ? 1.f : 0.f;
            const int r = rb + 64;
            const float2 kk = *(const float2*)&Kw[r][c];
            const float2 vv = *(const float2*)&Vw[r][c];
            const float b0 = m * fexp2(qsB0 * (kk.x + ppRoll.x));
            const float b1 = m * fexp2(qsB1 * (kk.y + ppRoll.y));
            dB0 += b0; nB0 += b0 * vv.x; dB1 += b1; nB1 += b1 * vv.y;
            dA0 += m;  nA0 += m * vv.x;  dA1 += m;  nA1 += m * vv.y;
        }
    }

    // sigmoid via raw exp2 (reuse qs = q*log2e): sig = 1/(1+2^-qs)
    const float sA0 = 1.f / (1.f + fexp2(-qsA0));
    const float sA1 = 1.f / (1.f + fexp2(-qsA1));
    const float sB0 = 1.f / (1.f + fexp2(-qsB0));
    const float sB1 = 1.f / (1.f + fexp2(-qsB1));

    float2 oA, oB;
    oA.x = sA0 * sA0 * nA0 / dA0;
    oA.y = sA1 * sA1 * nA1 / dA1;
    oB.x = sB0 * sB0 * nB0 / dB0;
    oB.y = sB1 * sB1 * nB1 / dB1;
    *(float2*)(out + ((size_t)b * L_ + iA) * E_ + c0 + c) = oA;
    *(float2*)(out + ((size_t)b * L_ + iB) * E_ + c0 + c) = oB;
}

// ===========================================================================
// PATH B (ws too small; fallback only): fully fused, fp32.
// ===========================================================================
#define TI 32
#define CG 64
#define RK 96
#define LDP 68

__global__ __launch_bounds__(256) void aft_fused(
    const float* __restrict__ q,
    const float* __restrict__ Wq, const float* __restrict__ bq,
    const float* __restrict__ Wk, const float* __restrict__ bk,
    const float* __restrict__ Wv, const float* __restrict__ bv,
    const float* __restrict__ pb,
    float* __restrict__ out)
{
    __shared__ float Kl[RK][LDP];
    __shared__ float Vl[RK][LDP];
    __shared__ float Ql[TI][LDP];

    const int i0 = blockIdx.x * TI;
    const int b  = blockIdx.y;
    const int c0 = blockIdx.z * CG;

    const int wave = threadIdx.x >> 6;
    const int lane = threadIdx.x & 63;
    const int rsel = lane & 15;
    const int koff = (lane >> 4) * 8;

    const float* qb = q + (size_t)b * L_ * E_;

    for (int job = wave; job < 56; job += 4) {
        int p, rt, ct;
        if (job < 24)      { p = 0; rt = job >> 2;        ct = job & 3; }
        else if (job < 48) { p = 1; rt = (job - 24) >> 2; ct = (job - 24) & 3; }
        else               { p = 2; rt = (job - 48) >> 2; ct = (job - 48) & 3; }

        int jrow = (p == 2) ? (i0 + rt * 16 + rsel)
                            : (i0 - S_ + rt * 16 + rsel);
        int jc = jrow < 0 ? 0 : (jrow > L_ - 1 ? L_ - 1 : jrow);
        const float* pa = qb + (size_t)jc * E_ + koff;

        const float* Wm = (p == 0) ? Wk : (p == 1) ? Wv : Wq;
        const float* bm = (p == 0) ? bk : (p == 1) ? bv : bq;
        const int n = c0 + ct * 16 + rsel;
        const float* pw = Wm + (size_t)n * E_ + koff;

        f32x4 acc = {0.f, 0.f, 0.f, 0.f};
#pragma unroll
        for (int k0 = 0; k0 < 256; k0 += 32) {
            bf16x8 ah, al, bh, bl;
            load8split(pa + k0, ah, al);
            load8split(pw + k0, bh, bl);
            acc = __builtin_amdgcn_mfma_f32_16x16x32_bf16(ah, bh, acc, 0, 0, 0);
            acc = __builtin_amdgcn_mfma_f32_16x16x32_bf16(ah, bl, acc, 0, 0, 0);
            acc = __builtin_amdgcn_mfma_f32_16x16x32_bf16(al, bh, acc, 0, 0, 0);
        }

        const float bias = bm[n];
        const int row0 = rt * 16 + (lane >> 4) * 4;
        const int colc = ct * 16 + rsel;
        float* dst = (p == 0) ? &Kl[0][0] : (p == 1) ? &Vl[0][0] : &Ql[0][0];
#pragma unroll
        for (int r = 0; r < 4; ++r)
            dst[(size_t)(row0 + r) * LDP + colc] = acc[r] + bias;
    }
    __syncthreads();

    const int cq  = threadIdx.x & 15;
    const int is0 = threadIdx.x >> 4;
    const int cL  = cq * 4;
    const int cG  = c0 + cL;
    const float* pbc = pb + cG;

    for (int rr = is0; rr < TI; rr += 16) {
        const int i = i0 + rr;
        const float4 qv = *(const float4*)&Ql[rr][cL];

        float den0 = 0.f, den1 = 0.f, den2 = 0.f, den3 = 0.f;
        float num0 = 0.f, num1 = 0.f, num2 = 0.f, num3 = 0.f;

        const int jlo = (i - S_ < 0) ? 0 : (i - S_);
        const int jhi = (i + S_ > L_ - 1) ? (L_ - 1) : (i + S_);

        for (int j = jlo; j <= jhi; ++j) {
            const int r = j - (i0 - S_);
            const int w = j - i + S_;
            const float4 vv = *(const float4*)&Vl[r][cL];

            float kx = 0.f, ky = 0.f, kz = 0.f, kw = 0.f;
            if (w != 0 && w != 2 * S_) {
                const float4 kk = *(const float4*)&Kl[r][cL];
                const float4 pp = *(const float4*)(pbc + (size_t)w * E_);
                kx = kk.x + pp.x;
                ky = kk.y + pp.y;
                kz = kk.z + pp.z;
                kw = kk.w + pp.w;
            }
            const float e0 = __expf(qv.x * kx);
            const float e1 = __expf(qv.y * ky);
            const float e2 = __expf(qv.z * kz);
            const float e3 = __expf(qv.w * kw);
            den0 += e0; den1 += e1; den2 += e2; den3 += e3;
            num0 += e0 * vv.x; num1 += e1 * vv.y;
            num2 += e2 * vv.z; num3 += e3 * vv.w;
        }

        const float s0 = 1.f / (1.f + __expf(-qv.x));
        const float s1 = 1.f / (1.f + __expf(-qv.y));
        const float s2 = 1.f / (1.f + __expf(-qv.z));
        const float s3 = 1.f / (1.f + __expf(-qv.w));

        float4 o;
        o.x = s0 * s0 * num0 / den0;
        o.y = s1 * s1 * num1 / den1;
        o.z = s2 * s2 * num2 / den2;
        o.w = s3 * s3 * num3 / den3;
        *(float4*)(out + ((size_t)b * L_ + i) * E_ + cG) = o;
    }
}

extern "C" void kernel_launch(void* const* d_in, const int* in_sizes, int n_in,
                              void* d_out, int out_size, void* d_ws, size_t ws_size,
                              hipStream_t stream) {
    const float* q  = (const float*)d_in[0];
    const float* Wq = (const float*)d_in[1];
    const float* bq = (const float*)d_in[2];
    const float* Wk = (const float*)d_in[3];
    const float* bk = (const float*)d_in[4];
    const float* Wv = (const float*)d_in[5];
    const float* bv = (const float*)d_in[6];
    const float* pb = (const float*)d_in[7];

    const size_t needA = (size_t)3 * 4096 * 256 * sizeof(float);  // 12.6 MB

    if (ws_size >= needA) {
        float* Qf = (float*)d_ws;
        float* Kf = Qf + (size_t)4096 * 256;
        float* Vf = Kf + (size_t)4096 * 256;
        qkv_gemm2<<<dim3(128, 1, 3), 256, 0, stream>>>(q, Wq, bq, Wk, bk, Wv, bv,
                                                       Qf, Kf, Vf);
        aft_stage2f<<<dim3(L_ / TI5, B_, E_ / CH5), 256, 0, stream>>>(
            Qf, Kf, Vf, pb, (float*)d_out);
    } else {
        aft_fused<<<dim3(L_ / TI, B_, E_ / CG), 256, 0, stream>>>(
            q, Wq, bq, Wk, bk, Wv, bv, pb, (float*)d_out);
    }
}

// Round 5
// 114.529 us; speedup vs baseline: 1.2177x; 1.0049x over previous
//
#include <hip/hip_runtime.h>
#include <hip/hip_bf16.h>

#define B_ 4
#define L_ 1024
#define E_ 256
#define S_ 32

typedef __bf16 bf16x8 __attribute__((ext_vector_type(8)));
typedef float f32x4 __attribute__((ext_vector_type(4)));

__device__ __forceinline__ __bf16 bf_from_bits(unsigned short u) {
    __bf16 b;
    __builtin_memcpy(&b, &u, 2);
    return b;
}

// Raw v_exp_f32 (2^x). libm exp2f lowers to the OCML denormal-correct wrapper
// (~5 VALU fixup/call); raw is safe here (denormal softmax terms ~ 0).
// Confirmed win round 4: -7.3 us.
__device__ __forceinline__ float fexp2(float x) {
#if __has_builtin(__builtin_amdgcn_exp2f)
    return __builtin_amdgcn_exp2f(x);
#else
    return exp2f(x);
#endif
}

// Split fp32 -> bf16 hi (truncate) + bf16 lo (residual). a ~= hi + lo with
// ~2^-17 rel error when both terms are used in the MFMA product expansion.
__device__ __forceinline__ void load8split(const float* __restrict__ p,
                                           bf16x8& h, bf16x8& l) {
    const float4 x0 = *(const float4*)p;
    const float4 x1 = *(const float4*)(p + 4);
    const float xs[8] = {x0.x, x0.y, x0.z, x0.w, x1.x, x1.y, x1.z, x1.w};
#pragma unroll
    for (int j = 0; j < 8; ++j) {
        const unsigned hb = __float_as_uint(xs[j]) & 0xFFFF0000u;
        h[j] = bf_from_bits((unsigned short)(hb >> 16));
        l[j] = (__bf16)(xs[j] - __uint_as_float(hb));
    }
}

// ===========================================================================
// PATH A kernel 1: Q/K/V projections (unchanged, ~5 us, near its floor).
// ===========================================================================
__global__ __launch_bounds__(256, 1) void qkv_gemm2(
    const float* __restrict__ A,
    const float* __restrict__ Wq, const float* __restrict__ bq,
    const float* __restrict__ Wk, const float* __restrict__ bk,
    const float* __restrict__ Wv, const float* __restrict__ bv,
    float* __restrict__ Qo, float* __restrict__ Ko, float* __restrict__ Vo)
{
    const float* Wm;
    const float* bm;
    float* Om;
    const int z = blockIdx.z;
    if (z == 0)      { Wm = Wq; bm = bq; Om = Qo; }
    else if (z == 1) { Wm = Wk; bm = bk; Om = Ko; }
    else             { Wm = Wv; bm = bv; Om = Vo; }

    const int wave = threadIdx.x >> 6;
    const int lane = threadIdx.x & 63;
    const int rsel = lane & 15;
    const int koff = (lane >> 4) * 8;

    const int m0 = blockIdx.x * 32;
    const int nb = wave * 64;

    const float* pa0 = A + (size_t)(m0 + rsel) * 256 + koff;
    const float* pa1 = pa0 + (size_t)16 * 256;
    const float* pw0 = Wm + (size_t)(nb + 0  + rsel) * 256 + koff;
    const float* pw1 = Wm + (size_t)(nb + 16 + rsel) * 256 + koff;
    const float* pw2 = Wm + (size_t)(nb + 32 + rsel) * 256 + koff;
    const float* pw3 = Wm + (size_t)(nb + 48 + rsel) * 256 + koff;

    f32x4 acc[2][4];
#pragma unroll
    for (int mt = 0; mt < 2; ++mt)
#pragma unroll
        for (int nt = 0; nt < 4; ++nt)
            acc[mt][nt] = (f32x4){0.f, 0.f, 0.f, 0.f};

#pragma unroll
    for (int k0 = 0; k0 < 256; k0 += 32) {
        bf16x8 ah[2], al[2], bh[4], bl[4];
        load8split(pa0 + k0, ah[0], al[0]);
        load8split(pa1 + k0, ah[1], al[1]);
        load8split(pw0 + k0, bh[0], bl[0]);
        load8split(pw1 + k0, bh[1], bl[1]);
        load8split(pw2 + k0, bh[2], bl[2]);
        load8split(pw3 + k0, bh[3], bl[3]);
#pragma unroll
        for (int mt = 0; mt < 2; ++mt)
#pragma unroll
            for (int nt = 0; nt < 4; ++nt) {
                acc[mt][nt] = __builtin_amdgcn_mfma_f32_16x16x32_bf16(
                    ah[mt], bh[nt], acc[mt][nt], 0, 0, 0);
                acc[mt][nt] = __builtin_amdgcn_mfma_f32_16x16x32_bf16(
                    ah[mt], bl[nt], acc[mt][nt], 0, 0, 0);
                acc[mt][nt] = __builtin_amdgcn_mfma_f32_16x16x32_bf16(
                    al[mt], bh[nt], acc[mt][nt], 0, 0, 0);
            }
    }

#pragma unroll
    for (int mt = 0; mt < 2; ++mt) {
        const int mrow = m0 + mt * 16 + (lane >> 4) * 4;
#pragma unroll
        for (int nt = 0; nt < 4; ++nt) {
            const int n = nb + nt * 16 + rsel;
            const float bias = bm[n];
#pragma unroll
            for (int r = 0; r < 4; ++r)
                Om[(size_t)(mrow + r) * 256 + n] = acc[mt][nt][r] + bias;
        }
    }
}

// ===========================================================================
// PATH A kernel 2 (v7): windowed per-channel softmax + context + sigmoid^2.
// 4-ROW PAIRING (extends v5/v6's 2-row sharing): thread owns rows iA..iA+3
// and 2 channels. One K/V LDS read per j-step feeds 4 row-taps; pos_bias
// rolls through a 4-deep register history (p0,h1,h2,h3 rotated in a manually
// 4x-unrolled body -> all LDS indices compile-time, no scratch).
// DS per CU: 8 waves x 68 steps x 3 ds_read_b64 x 6cy ~ 9.8k cy ~ 4.1 us
// (was 7.7); VALU/trans issue ~7.2 us/SIMD now binds. Block 128 thr
// (8 row-quads x 16 channel-duos), grid 1024 = 4 blk/CU = 8 waves/CU.
// w=0 / w=64 strict-mask taps peeled into head (t=0..3) / tail (t=64..67);
// edge x-blocks (0, 31) take a fully j-masked clone.
// ===========================================================================
#define TI7 32          // i-rows per block (8 quads)
#define CH7 32          // channels per block
#define HR7 96          // staged rows: j in [i0-S, i0+TI7-1+S]
#define PS7 36          // padded LDS stride (floats)

// Regular 4-row step, interior (all j valid). PNEW <- Pw[T]; rows 1..3 use
// the history PH1=P[T-1], PH2=P[T-2], PH3=P[T-3].
#define STEP4I(T, PNEW, PH1, PH2, PH3)                                   \
    {                                                                    \
        const int rl = rb + (T);                                         \
        const float2 kk = *(const float2*)&Kw[rl][c];                    \
        const float2 vv = *(const float2*)&Vw[rl][c];                    \
        PNEW = *(const float2*)&Pw[(T)][c];                              \
        const float e0x = fexp2(qs0x * (kk.x + PNEW.x));                 \
        const float e0y = fexp2(qs0y * (kk.y + PNEW.y));                 \
        const float e1x = fexp2(qs1x * (kk.x + PH1.x));                  \
        const float e1y = fexp2(qs1y * (kk.y + PH1.y));                  \
        const float e2x = fexp2(qs2x * (kk.x + PH2.x));                  \
        const float e2y = fexp2(qs2y * (kk.y + PH2.y));                  \
        const float e3x = fexp2(qs3x * (kk.x + PH3.x));                  \
        const float e3y = fexp2(qs3y * (kk.y + PH3.y));                  \
        d0x += e0x; n0x += e0x * vv.x; d0y += e0y; n0y += e0y * vv.y;    \
        d1x += e1x; n1x += e1x * vv.x; d1y += e1y; n1y += e1y * vv.y;    \
        d2x += e2x; n2x += e2x * vv.x; d2y += e2y; n2y += e2y * vv.y;    \
        d3x += e3x; n3x += e3x * vv.x; d3y += e3y; n3y += e3y * vv.y;    \
    }

// Edge-block variant: every term masked by m = (j in [0, L-1]); j is shared
// by all 4 rows at a given step.
#define STEP4E(T, PNEW, PH1, PH2, PH3)                                   \
    {                                                                    \
        const int jj = iA - S_ + (T);                                    \
        const float m = (jj >= 0 && jj <= L_ - 1) ? 1.f : 0.f;           \
        const int rl = rb + (T);                                         \
        const float2 kk = *(const float2*)&Kw[rl][c];                    \
        const float2 vv = *(const float2*)&Vw[rl][c];                    \
        PNEW = *(const float2*)&Pw[(T)][c];                              \
        const float e0x = m * fexp2(qs0x * (kk.x + PNEW.x));             \
        const float e0y = m * fexp2(qs0y * (kk.y + PNEW.y));             \
        const float e1x = m * fexp2(qs1x * (kk.x + PH1.x));              \
        const float e1y = m * fexp2(qs1y * (kk.y + PH1.y));              \
        const float e2x = m * fexp2(qs2x * (kk.x + PH2.x));              \
        const float e2y = m * fexp2(qs2y * (kk.y + PH2.y));              \
        const float e3x = m * fexp2(qs3x * (kk.x + PH3.x));              \
        const float e3y = m * fexp2(qs3y * (kk.y + PH3.y));              \
        d0x += e0x; n0x += e0x * vv.x; d0y += e0y; n0y += e0y * vv.y;    \
        d1x += e1x; n1x += e1x * vv.x; d1y += e1y; n1y += e1y * vv.y;    \
        d2x += e2x; n2x += e2x * vv.x; d2y += e2y; n2y += e2y * vv.y;    \
        d3x += e3x; n3x += e3x * vv.x; d3y += e3y; n3y += e3y * vv.y;    \
    }

__global__ __launch_bounds__(128, 2) void aft_stage2g(
    const float* __restrict__ Q, const float* __restrict__ K,
    const float* __restrict__ V, const float* __restrict__ pb,
    float* __restrict__ out)
{
    __shared__ float Kw[HR7][PS7];        // 13824 B
    __shared__ float Vw[HR7][PS7];        // 13824 B
    __shared__ float Pw[2 * S_ + 1][PS7]; //  9360 B (total 37008 B, 4 blk/CU)

    const int tid = threadIdx.x;          // 0..127
    const int b  = blockIdx.y;
    const int i0 = blockIdx.x * TI7;
    const int c0 = blockIdx.z * CH7;

    const int duo = tid & 15;             // channel duo 0..15
    const int qd  = tid >> 4;             // row quad 0..7
    const int c   = duo * 2;
    const int iA  = i0 + qd * 4;          // rows iA .. iA+3
    const int rb  = qd * 4;               // LDS row of j = iA - S at t=0

    // Q reads issued before staging; complete under the barrier.
    const float* Qr = Q + ((size_t)b * L_ + iA) * E_ + c0 + c;
    const float2 qv0 = *(const float2*)(Qr);
    const float2 qv1 = *(const float2*)(Qr + E_);
    const float2 qv2 = *(const float2*)(Qr + 2 * E_);
    const float2 qv3 = *(const float2*)(Qr + 3 * E_);

    const float* Kb = K + (size_t)b * L_ * E_;
    const float* Vb = V + (size_t)b * L_ * E_;

    // ---- stage K/V halo rows (96 rows x 32 ch), 128 threads ----
    for (int idx = tid; idx < HR7 * 8; idx += 128) {
        const int r = idx >> 3;
        const int cc = (idx & 7) * 4;
        int j = i0 - S_ + r;
        j = j < 0 ? 0 : (j > L_ - 1 ? L_ - 1 : j);   // clamped rows are masked
        const size_t g = (size_t)j * E_ + c0 + cc;
        *(float4*)&Kw[r][cc] = *(const float4*)(Kb + g);
        *(float4*)&Vw[r][cc] = *(const float4*)(Vb + g);
    }
    // ---- stage pos_bias slice (65 rows x 32 ch) ----
    for (int idx = tid; idx < (2 * S_ + 1) * 8; idx += 128) {
        const int r = idx >> 3;
        const int cc = (idx & 7) * 4;
        *(float4*)&Pw[r][cc] = *(const float4*)(pb + (size_t)r * E_ + c0 + cc);
    }
    __syncthreads();

    const float LOG2E = 1.44269504088896340736f;
    const float qs0x = qv0.x * LOG2E, qs0y = qv0.y * LOG2E;
    const float qs1x = qv1.x * LOG2E, qs1y = qv1.y * LOG2E;
    const float qs2x = qv2.x * LOG2E, qs2y = qv2.y * LOG2E;
    const float qs3x = qv3.x * LOG2E, qs3y = qv3.y * LOG2E;

    float d0x = 0.f, d0y = 0.f, n0x = 0.f, n0y = 0.f;
    float d1x = 0.f, d1y = 0.f, n1x = 0.f, n1y = 0.f;
    float d2x = 0.f, d2y = 0.f, n2x = 0.f, n2y = 0.f;
    float d3x = 0.f, d3y = 0.f, n3x = 0.f, n3y = 0.f;

    float2 p0, h1, h2, h3;

    const bool interior = (blockIdx.x >= 1) && (blockIdx.x <= (L_ / TI7) - 2);

    if (interior) {
        // ---- head t=0..3: w=0 peels (e=1) + early regular taps ----
        {   // t=0: row0 peel only
            const float2 vv = *(const float2*)&Vw[rb][c];
            d0x += 1.f; n0x += vv.x; d0y += 1.f; n0y += vv.y;
        }
        {   // t=1: row0 w=1; row1 peel
            const float2 kk = *(const float2*)&Kw[rb + 1][c];
            const float2 vv = *(const float2*)&Vw[rb + 1][c];
            h3 = *(const float2*)&Pw[1][c];               // P[1]
            const float e0x = fexp2(qs0x * (kk.x + h3.x));
            const float e0y = fexp2(qs0y * (kk.y + h3.y));
            d0x += e0x; n0x += e0x * vv.x; d0y += e0y; n0y += e0y * vv.y;
            d1x += 1.f; n1x += vv.x;       d1y += 1.f; n1y += vv.y;
        }
        {   // t=2: row0 w=2; row1 w=1; row2 peel
            const float2 kk = *(const float2*)&Kw[rb + 2][c];
            const float2 vv = *(const float2*)&Vw[rb + 2][c];
            h2 = *(const float2*)&Pw[2][c];               // P[2]
            const float e0x = fexp2(qs0x * (kk.x + h2.x));
            const float e0y = fexp2(qs0y * (kk.y + h2.y));
            const float e1x = fexp2(qs1x * (kk.x + h3.x));
            const float e1y = fexp2(qs1y * (kk.y + h3.y));
            d0x += e0x; n0x += e0x * vv.x; d0y += e0y; n0y += e0y * vv.y;
            d1x += e1x; n1x += e1x * vv.x; d1y += e1y; n1y += e1y * vv.y;
            d2x += 1.f; n2x += vv.x;       d2y += 1.f; n2y += vv.y;
        }
        {   // t=3: row0 w=3; row1 w=2; row2 w=1; row3 peel
            const float2 kk = *(const float2*)&Kw[rb + 3][c];
            const float2 vv = *(const float2*)&Vw[rb + 3][c];
            h1 = *(const float2*)&Pw[3][c];               // P[3]
            const float e0x = fexp2(qs0x * (kk.x + h1.x));
            const float e0y = fexp2(qs0y * (kk.y + h1.y));
            const float e1x = fexp2(qs1x * (kk.x + h2.x));
            const float e1y = fexp2(qs1y * (kk.y + h2.y));
            const float e2x = fexp2(qs2x * (kk.x + h3.x));
            const float e2y = fexp2(qs2y * (kk.y + h3.y));
            d0x += e0x; n0x += e0x * vv.x; d0y += e0y; n0y += e0y * vv.y;
            d1x += e1x; n1x += e1x * vv.x; d1y += e1y; n1y += e1y * vv.y;
            d2x += e2x; n2x += e2x * vv.x; d2y += e2y; n2y += e2y * vv.y;
            d3x += 1.f; n3x += vv.x;       d3y += 1.f; n3y += vv.y;
        }
        // entry invariant: h1=P[t-1], h2=P[t-2], h3=P[t-3]
#pragma unroll 2
        for (int t = 4; t <= 60; t += 4) {
            STEP4I(t + 0, p0, h1, h2, h3)
            STEP4I(t + 1, h3, p0, h1, h2)
            STEP4I(t + 2, h2, h3, p0, h1)
            STEP4I(t + 3, h1, h2, h3, p0)
        }
        // after loop: h1=P[63], h2=P[62], h3=P[61]
        // ---- tail t=64..67: w=64 peels (e=1) + late regular taps ----
        {   // t=64: row0 peel; row1 w=63(h1); row2 w=62(h2); row3 w=61(h3)
            const float2 kk = *(const float2*)&Kw[rb + 64][c];
            const float2 vv = *(const float2*)&Vw[rb + 64][c];
            const float e1x = fexp2(qs1x * (kk.x + h1.x));
            const float e1y = fexp2(qs1y * (kk.y + h1.y));
            const float e2x = fexp2(qs2x * (kk.x + h2.x));
            const float e2y = fexp2(qs2y * (kk.y + h2.y));
            const float e3x = fexp2(qs3x * (kk.x + h3.x));
            const float e3y = fexp2(qs3y * (kk.y + h3.y));
            d0x += 1.f; n0x += vv.x;       d0y += 1.f; n0y += vv.y;
            d1x += e1x; n1x += e1x * vv.x; d1y += e1y; n1y += e1y * vv.y;
            d2x += e2x; n2x += e2x * vv.x; d2y += e2y; n2y += e2y * vv.y;
            d3x += e3x; n3x += e3x * vv.x; d3y += e3y; n3y += e3y * vv.y;
        }
        {   // t=65: row1 peel; row2 w=63(h1); row3 w=62(h2)
            const float2 kk = *(const float2*)&Kw[rb + 65][c];
            const float2 vv = *(const float2*)&Vw[rb + 65][c];
            const float e2x = fexp2(qs2x * (kk.x + h1.x));
            const float e2y = fexp2(qs2y * (kk.y + h1.y));
            const float e3x = fexp2(qs3x * (kk.x + h2.x));
            const float e3y = fexp2(qs3y * (kk.y + h2.y));
            d1x += 1.f; n1x += vv.x;       d1y += 1.f; n1y += vv.y;
            d2x += e2x; n2x += e2x * vv.x; d2y += e2y; n2y += e2y * vv.y;
            d3x += e3x; n3x += e3x * vv.x; d3y += e3y; n3y += e3y * vv.y;
        }
        {   // t=66: row2 peel; row3 w=63(h1)
            const float2 kk = *(const float2*)&Kw[rb + 66][c];
            const float2 vv = *(const float2*)&Vw[rb + 66][c];
            const float e3x = fexp2(qs3x * (kk.x + h1.x));
            const float e3y = fexp2(qs3y * (kk.y + h1.y));
            d2x += 1.f; n2x += vv.x;       d2y += 1.f; n2y += vv.y;
            d3x += e3x; n3x += e3x * vv.x; d3y += e3y; n3y += e3y * vv.y;
        }
        {   // t=67: row3 peel
            const float2 vv = *(const float2*)&Vw[rb + 67][c];
            d3x += 1.f; n3x += vv.x; d3y += 1.f; n3y += vv.y;
        }
    } else {
        // ---- edge blocks: every step masked by j-validity (shared by rows) ----
        {   // t=0: row0 peel
            const int jj = iA - S_;
            const float m = (jj >= 0) ? 1.f : 0.f;
            const float2 vv = *(const float2*)&Vw[rb][c];
            d0x += m; n0x += m * vv.x; d0y += m; n0y += m * vv.y;
        }
        {   // t=1
            const int jj = iA - S_ + 1;
            const float m = (jj >= 0 && jj <= L_ - 1) ? 1.f : 0.f;
            const float2 kk = *(const float2*)&Kw[rb + 1][c];
            const float2 vv = *(const float2*)&Vw[rb + 1][c];
            h3 = *(const float2*)&Pw[1][c];
            const float e0x = m * fexp2(qs0x * (kk.x + h3.x));
            const float e0y = m * fexp2(qs0y * (kk.y + h3.y));
            d0x += e0x; n0x += e0x * vv.x; d0y += e0y; n0y += e0y * vv.y;
            d1x += m;   n1x += m * vv.x;   d1y += m;   n1y += m * vv.y;
        }
        {   // t=2
            const int jj = iA - S_ + 2;
            const float m = (jj >= 0 && jj <= L_ - 1) ? 1.f : 0.f;
            const float2 kk = *(const float2*)&Kw[rb + 2][c];
            const float2 vv = *(const float2*)&Vw[rb + 2][c];
            h2 = *(const float2*)&Pw[2][c];
            const float e0x = m * fexp2(qs0x * (kk.x + h2.x));
            const float e0y = m * fexp2(qs0y * (kk.y + h2.y));
            const float e1x = m * fexp2(qs1x * (kk.x + h3.x));
            const float e1y = m * fexp2(qs1y * (kk.y + h3.y));
            d0x += e0x; n0x += e0x * vv.x; d0y += e0y; n0y += e0y * vv.y;
            d1x += e1x; n1x += e1x * vv.x; d1y += e1y; n1y += e1y * vv.y;
            d2x += m;   n2x += m * vv.x;   d2y += m;   n2y += m * vv.y;
        }
        {   // t=3
            const int jj = iA - S_ + 3;
            const float m = (jj >= 0 && jj <= L_ - 1) ? 1.f : 0.f;
            const float2 kk = *(const float2*)&Kw[rb + 3][c];
            const float2 vv = *(const float2*)&Vw[rb + 3][c];
            h1 = *(const float2*)&Pw[3][c];
            const float e0x = m * fexp2(qs0x * (kk.x + h1.x));
            const float e0y = m * fexp2(qs0y * (kk.y + h1.y));
            const float e1x = m * fexp2(qs1x * (kk.x + h2.x));
            const float e1y = m * fexp2(qs1y * (kk.y + h2.y));
            const float e2x = m * fexp2(qs2x * (kk.x + h3.x));
            const float e2y = m * fexp2(qs2y * (kk.y + h3.y));
            d0x += e0x; n0x += e0x * vv.x; d0y += e0y; n0y += e0y * vv.y;
            d1x += e1x; n1x += e1x * vv.x; d1y += e1y; n1y += e1y * vv.y;
            d2x += e2x; n2x += e2x * vv.x; d2y += e2y; n2y += e2y * vv.y;
            d3x += m;   n3x += m * vv.x;   d3y += m;   n3y += m * vv.y;
        }
#pragma unroll 2
        for (int t = 4; t <= 60; t += 4) {
            STEP4E(t + 0, p0, h1, h2, h3)
            STEP4E(t + 1, h3, p0, h1, h2)
            STEP4E(t + 2, h2, h3, p0, h1)
            STEP4E(t + 3, h1, h2, h3, p0)
        }
        {   // t=64
            const int jj = iA - S_ + 64;
            const float m = (jj >= 0 && jj <= L_ - 1) ? 1.f : 0.f;
            const float2 kk = *(const float2*)&Kw[rb + 64][c];
            const float2 vv = *(const float2*)&Vw[rb + 64][c];
            const float e1x = m * fexp2(qs1x * (kk.x + h1.x));
            const float e1y = m * fexp2(qs1y * (kk.y + h1.y));
            const float e2x = m * fexp2(qs2x * (kk.x + h2.x));
            const float e2y = m * fexp2(qs2y * (kk.y + h2.y));
            const float e3x = m * fexp2(qs3x * (kk.x + h3.x));
            const float e3y = m * fexp2(qs3y * (kk.y + h3.y));
            d0x += m;   n0x += m * vv.x;   d0y += m;   n0y += m * vv.y;
            d1x += e1x; n1x += e1x * vv.x; d1y += e1y; n1y += e1y * vv.y;
            d2x += e2x; n2x += e2x * vv.x; d2y += e2y; n2y += e2y * vv.y;
            d3x += e3x; n3x += e3x * vv.x; d3y += e3y; n3y += e3y * vv.y;
        }
        {   // t=65
            const int jj = iA - S_ + 65;
            const float m = (jj >= 0 && jj <= L_ - 1) ? 1.f : 0.f;
            const float2 kk = *(const float2*)&Kw[rb + 65][c];
            const float2 vv = *(const float2*)&Vw[rb + 65][c];
            const float e2x = m * fexp2(qs2x * (kk.x + h1.x));
            const float e2y = m * fexp2(qs2y * (kk.y + h1.y));
            const float e3x = m * fexp2(qs3x * (kk.x + h2.x));
            const float e3y = m * fexp2(qs3y * (kk.y + h2.y));
            d1x += m;   n1x += m * vv.x;   d1y += m;   n1y += m * vv.y;
            d2x += e2x; n2x += e2x * vv.x; d2y += e2y; n2y += e2y * vv.y;
            d3x += e3x; n3x += e3x * vv.x; d3y += e3y; n3y += e3y * vv.y;
        }
        {   // t=66
            const int jj = iA - S_ + 66;
            const float m = (jj >= 0 && jj <= L_ - 1) ? 1.f : 0.f;
            const float2 kk = *(const float2*)&Kw[rb + 66][c];
            const float2 vv = *(const float2*)&Vw[rb + 66][c];
            const float e3x = m * fexp2(qs3x * (kk.x + h1.x));
            const float e3y = m * fexp2(qs3y * (kk.y + h1.y));
            d2x += m;   n2x += m * vv.x;   d2y += m;   n2y += m * vv.y;
            d3x += e3x; n3x += e3x * vv.x; d3y += e3y; n3y += e3y * vv.y;
        }
        {   // t=67
            const int jj = iA - S_ + 67;
            const float m = (jj >= 0 && jj <= L_ - 1) ? 1.f : 0.f;
            const float2 vv = *(const float2*)&Vw[rb + 67][c];
            d3x += m; n3x += m * vv.x; d3y += m; n3y += m * vv.y;
        }
    }

    // sigmoid via raw exp2 (reuse qs = q*log2e): sig = 1/(1+2^-qs)
    const float s0x = 1.f / (1.f + fexp2(-qs0x));
    const float s0y = 1.f / (1.f + fexp2(-qs0y));
    const float s1x = 1.f / (1.f + fexp2(-qs1x));
    const float s1y = 1.f / (1.f + fexp2(-qs1y));
    const float s2x = 1.f / (1.f + fexp2(-qs2x));
    const float s2y = 1.f / (1.f + fexp2(-qs2y));
    const float s3x = 1.f / (1.f + fexp2(-qs3x));
    const float s3y = 1.f / (1.f + fexp2(-qs3y));

    float* ob = out + ((size_t)b * L_ + iA) * E_ + c0 + c;
    float2 o;
    o.x = s0x * s0x * n0x / d0x; o.y = s0y * s0y * n0y / d0y;
    *(float2*)(ob) = o;
    o.x = s1x * s1x * n1x / d1x; o.y = s1y * s1y * n1y / d1y;
    *(float2*)(ob + E_) = o;
    o.x = s2x * s2x * n2x / d2x; o.y = s2y * s2y * n2y / d2y;
    *(float2*)(ob + 2 * E_) = o;
    o.x = s3x * s3x * n3x / d3x; o.y = s3y * s3y * n3y / d3y;
    *(float2*)(ob + 3 * E_) = o;
}

// ===========================================================================
// PATH B (ws too small; fallback only): fully fused, fp32.
// ===========================================================================
#define TI 32
#define CG 64
#define RK 96
#define LDP 68

__global__ __launch_bounds__(256) void aft_fused(
    const float* __restrict__ q,
    const float* __restrict__ Wq, const float* __restrict__ bq,
    const float* __restrict__ Wk, const float* __restrict__ bk,
    const float* __restrict__ Wv, const float* __restrict__ bv,
    const float* __restrict__ pb,
    float* __restrict__ out)
{
    __shared__ float Kl[RK][LDP];
    __shared__ float Vl[RK][LDP];
    __shared__ float Ql[TI][LDP];

    const int i0 = blockIdx.x * TI;
    const int b  = blockIdx.y;
    const int c0 = blockIdx.z * CG;

    const int wave = threadIdx.x >> 6;
    const int lane = threadIdx.x & 63;
    const int rsel = lane & 15;
    const int koff = (lane >> 4) * 8;

    const float* qb = q + (size_t)b * L_ * E_;

    for (int job = wave; job < 56; job += 4) {
        int p, rt, ct;
        if (job < 24)      { p = 0; rt = job >> 2;        ct = job & 3; }
        else if (job < 48) { p = 1; rt = (job - 24) >> 2; ct = (job - 24) & 3; }
        else               { p = 2; rt = (job - 48) >> 2; ct = (job - 48) & 3; }

        int jrow = (p == 2) ? (i0 + rt * 16 + rsel)
                            : (i0 - S_ + rt * 16 + rsel);
        int jc = jrow < 0 ? 0 : (jrow > L_ - 1 ? L_ - 1 : jrow);
        const float* pa = qb + (size_t)jc * E_ + koff;

        const float* Wm = (p == 0) ? Wk : (p == 1) ? Wv : Wq;
        const float* bm = (p == 0) ? bk : (p == 1) ? bv : bq;
        const int n = c0 + ct * 16 + rsel;
        const float* pw = Wm + (size_t)n * E_ + koff;

        f32x4 acc = {0.f, 0.f, 0.f, 0.f};
#pragma unroll
        for (int k0 = 0; k0 < 256; k0 += 32) {
            bf16x8 ah, al, bh, bl;
            load8split(pa + k0, ah, al);
            load8split(pw + k0, bh, bl);
            acc = __builtin_amdgcn_mfma_f32_16x16x32_bf16(ah, bh, acc, 0, 0, 0);
            acc = __builtin_amdgcn_mfma_f32_16x16x32_bf16(ah, bl, acc, 0, 0, 0);
            acc = __builtin_amdgcn_mfma_f32_16x16x32_bf16(al, bh, acc, 0, 0, 0);
        }

        const float bias = bm[n];
        const int row0 = rt * 16 + (lane >> 4) * 4;
        const int colc = ct * 16 + rsel;
        float* dst = (p == 0) ? &Kl[0][0] : (p == 1) ? &Vl[0][0] : &Ql[0][0];
#pragma unroll
        for (int r = 0; r < 4; ++r)
            dst[(size_t)(row0 + r) * LDP + colc] = acc[r] + bias;
    }
    __syncthreads();

    const int cq  = threadIdx.x & 15;
    const int is0 = threadIdx.x >> 4;
    const int cL  = cq * 4;
    const int cG  = c0 + cL;
    const float* pbc = pb + cG;

    for (int rr = is0; rr < TI; rr += 16) {
        const int i = i0 + rr;
        const float4 qv = *(const float4*)&Ql[rr][cL];

        float den0 = 0.f, den1 = 0.f, den2 = 0.f, den3 = 0.f;
        float num0 = 0.f, num1 = 0.f, num2 = 0.f, num3 = 0.f;

        const int jlo = (i - S_ < 0) ? 0 : (i - S_);
        const int jhi = (i + S_ > L_ - 1) ? (L_ - 1) : (i + S_);

        for (int j = jlo; j <= jhi; ++j) {
            const int r = j - (i0 - S_);
            const int w = j - i + S_;
            const float4 vv = *(const float4*)&Vl[r][cL];

            float kx = 0.f, ky = 0.f, kz = 0.f, kw = 0.f;
            if (w != 0 && w != 2 * S_) {
                const float4 kk = *(const float4*)&Kl[r][cL];
                const float4 pp = *(const float4*)(pbc + (size_t)w * E_);
                kx = kk.x + pp.x;
                ky = kk.y + pp.y;
                kz = kk.z + pp.z;
                kw = kk.w + pp.w;
            }
            const float e0 = __expf(qv.x * kx);
            const float e1 = __expf(qv.y * ky);
            const float e2 = __expf(qv.z * kz);
            const float e3 = __expf(qv.w * kw);
            den0 += e0; den1 += e1; den2 += e2; den3 += e3;
            num0 += e0 * vv.x; num1 += e1 * vv.y;
            num2 += e2 * vv.z; num3 += e3 * vv.w;
        }

        const float s0 = 1.f / (1.f + __expf(-qv.x));
        const float s1 = 1.f / (1.f + __expf(-qv.y));
        const float s2 = 1.f / (1.f + __expf(-qv.z));
        const float s3 = 1.f / (1.f + __expf(-qv.w));

        float4 o;
        o.x = s0 * s0 * num0 / den0;
        o.y = s1 * s1 * num1 / den1;
        o.z = s2 * s2 * num2 / den2;
        o.w = s3 * s3 * num3 / den3;
        *(float4*)(out + ((size_t)b * L_ + i) * E_ + cG) = o;
    }
}

extern "C" void kernel_launch(void* const* d_in, const int* in_sizes, int n_in,
                              void* d_out, int out_size, void* d_ws, size_t ws_size,
                              hipStream_t stream) {
    const float* q  = (const float*)d_in[0];
    const float* Wq = (const float*)d_in[1];
    const float* bq = (const float*)d_in[2];
    const float* Wk = (const float*)d_in[3];
    const float* bk = (const float*)d_in[4];
    const float* Wv = (const float*)d_in[5];
    const float* bv = (const float*)d_in[6];
    const float* pb = (const float*)d_in[7];

    const size_t needA = (size_t)3 * 4096 * 256 * sizeof(float);  // 12.6 MB

    if (ws_size >= needA) {
        float* Qf = (float*)d_ws;
        float* Kf = Qf + (size_t)4096 * 256;
        float* Vf = Kf + (size_t)4096 * 256;
        qkv_gemm2<<<dim3(128, 1, 3), 256, 0, stream>>>(q, Wq, bq, Wk, bk, Wv, bv,
                                                       Qf, Kf, Vf);
        aft_stage2g<<<dim3(L_ / TI7, B_, E_ / CH7), 128, 0, stream>>>(
            Qf, Kf, Vf, pb, (float*)d_out);
    } else {
        aft_fused<<<dim3(L_ / TI, B_, E_ / CG), 256, 0, stream>>>(
            q, Wq, bq, Wk, bk, Wv, bv, pb, (float*)d_out);
    }
}

// Round 6
// 112.942 us; speedup vs baseline: 1.2348x; 1.0141x over previous
//
#include <hip/hip_runtime.h>
#include <hip/hip_bf16.h>

#define B_ 4
#define L_ 1024
#define E_ 256
#define S_ 32

typedef __bf16 bf16x8 __attribute__((ext_vector_type(8)));
typedef float f32x4 __attribute__((ext_vector_type(4)));
typedef float f32x2 __attribute__((ext_vector_type(2)));

__device__ __forceinline__ __bf16 bf_from_bits(unsigned short u) {
    __bf16 b;
    __builtin_memcpy(&b, &u, 2);
    return b;
}

// Raw v_exp_f32 (2^x). libm exp2f lowers to the OCML denormal-correct wrapper
// (~5 VALU fixup/call); raw is safe here (denormal softmax terms ~ 0).
// Confirmed win round 4.
__device__ __forceinline__ float fexp2(float x) {
#if __has_builtin(__builtin_amdgcn_exp2f)
    return __builtin_amdgcn_exp2f(x);
#else
    return exp2f(x);
#endif
}

__device__ __forceinline__ f32x2 vexp2(f32x2 t) {
    f32x2 r;
    r.x = fexp2(t.x);
    r.y = fexp2(t.y);
    return r;
}

// Split fp32 -> bf16 hi (truncate) + bf16 lo (residual). a ~= hi + lo with
// ~2^-17 rel error when both terms are used in the MFMA product expansion.
__device__ __forceinline__ void load8split(const float* __restrict__ p,
                                           bf16x8& h, bf16x8& l) {
    const float4 x0 = *(const float4*)p;
    const float4 x1 = *(const float4*)(p + 4);
    const float xs[8] = {x0.x, x0.y, x0.z, x0.w, x1.x, x1.y, x1.z, x1.w};
#pragma unroll
    for (int j = 0; j < 8; ++j) {
        const unsigned hb = __float_as_uint(xs[j]) & 0xFFFF0000u;
        h[j] = bf_from_bits((unsigned short)(hb >> 16));
        l[j] = (__bf16)(xs[j] - __uint_as_float(hb));
    }
}

// ===========================================================================
// PATH A kernel 1: Q/K/V projections (unchanged, ~5 us, near its floor;
// a 16-row-tile rebalance was evaluated and rejected: load/MFMA ratio
// worsens 0.25 -> 0.42, net ~0).
// ===========================================================================
__global__ __launch_bounds__(256, 1) void qkv_gemm2(
    const float* __restrict__ A,
    const float* __restrict__ Wq, const float* __restrict__ bq,
    const float* __restrict__ Wk, const float* __restrict__ bk,
    const float* __restrict__ Wv, const float* __restrict__ bv,
    float* __restrict__ Qo, float* __restrict__ Ko, float* __restrict__ Vo)
{
    const float* Wm;
    const float* bm;
    float* Om;
    const int z = blockIdx.z;
    if (z == 0)      { Wm = Wq; bm = bq; Om = Qo; }
    else if (z == 1) { Wm = Wk; bm = bk; Om = Ko; }
    else             { Wm = Wv; bm = bv; Om = Vo; }

    const int wave = threadIdx.x >> 6;
    const int lane = threadIdx.x & 63;
    const int rsel = lane & 15;
    const int koff = (lane >> 4) * 8;

    const int m0 = blockIdx.x * 32;
    const int nb = wave * 64;

    const float* pa0 = A + (size_t)(m0 + rsel) * 256 + koff;
    const float* pa1 = pa0 + (size_t)16 * 256;
    const float* pw0 = Wm + (size_t)(nb + 0  + rsel) * 256 + koff;
    const float* pw1 = Wm + (size_t)(nb + 16 + rsel) * 256 + koff;
    const float* pw2 = Wm + (size_t)(nb + 32 + rsel) * 256 + koff;
    const float* pw3 = Wm + (size_t)(nb + 48 + rsel) * 256 + koff;

    f32x4 acc[2][4];
#pragma unroll
    for (int mt = 0; mt < 2; ++mt)
#pragma unroll
        for (int nt = 0; nt < 4; ++nt)
            acc[mt][nt] = (f32x4){0.f, 0.f, 0.f, 0.f};

#pragma unroll
    for (int k0 = 0; k0 < 256; k0 += 32) {
        bf16x8 ah[2], al[2], bh[4], bl[4];
        load8split(pa0 + k0, ah[0], al[0]);
        load8split(pa1 + k0, ah[1], al[1]);
        load8split(pw0 + k0, bh[0], bl[0]);
        load8split(pw1 + k0, bh[1], bl[1]);
        load8split(pw2 + k0, bh[2], bl[2]);
        load8split(pw3 + k0, bh[3], bl[3]);
#pragma unroll
        for (int mt = 0; mt < 2; ++mt)
#pragma unroll
            for (int nt = 0; nt < 4; ++nt) {
                acc[mt][nt] = __builtin_amdgcn_mfma_f32_16x16x32_bf16(
                    ah[mt], bh[nt], acc[mt][nt], 0, 0, 0);
                acc[mt][nt] = __builtin_amdgcn_mfma_f32_16x16x32_bf16(
                    ah[mt], bl[nt], acc[mt][nt], 0, 0, 0);
                acc[mt][nt] = __builtin_amdgcn_mfma_f32_16x16x32_bf16(
                    al[mt], bh[nt], acc[mt][nt], 0, 0, 0);
            }
    }

#pragma unroll
    for (int mt = 0; mt < 2; ++mt) {
        const int mrow = m0 + mt * 16 + (lane >> 4) * 4;
#pragma unroll
        for (int nt = 0; nt < 4; ++nt) {
            const int n = nb + nt * 16 + rsel;
            const float bias = bm[n];
#pragma unroll
            for (int r = 0; r < 4; ++r)
                Om[(size_t)(mrow + r) * 256 + n] = acc[mt][nt][r] + bias;
        }
    }
}

// ===========================================================================
// PATH A kernel 2 (v8): windowed per-channel softmax + context + sigmoid^2.
// Structure = v7 (4-row pairing, 2ch/thread, 128-thr blocks, rolling P
// history). Single change: ALL channel-pair arithmetic rewritten as
// ext_vector_type(2) float ops so clang forms packed-f32 VALU
// (v_pk_add_f32 / v_pk_mul_f32 / v_pk_fma_f32, CDNA2+). Interior step:
// 16 packed VALU + 8 v_exp_f32 + 3 ds_read_b64 (was 32 scalar VALU).
// Rationale: v6 (4 waves/SIMD, DS 7.7us) == v7 (2 waves/SIMD, DS 4.1us)
// within 0.6us -> neither DS nor occupancy binds; VALU issue + trans are
// the remaining compressible/irreducible pair.
// ===========================================================================
#define TI7 32          // i-rows per block (8 quads)
#define CH7 32          // channels per block
#define HR7 96          // staged rows: j in [i0-S, i0+TI7-1+S]
#define PS7 36          // padded LDS stride (floats); quad rows alias 2-way (free)

// Regular 4-row step, interior (all j valid). PNEW <- Pw[T]; rows 1..3 use
// history PH1=P[T-1], PH2=P[T-2], PH3=P[T-3]. All f32x2 vector ops.
#define STEP4I(T, PNEW, PH1, PH2, PH3)                                   \
    {                                                                    \
        const int rl = rb + (T);                                         \
        const f32x2 kk = *(const f32x2*)&Kw[rl][c];                      \
        const f32x2 vv = *(const f32x2*)&Vw[rl][c];                      \
        PNEW = *(const f32x2*)&Pw[(T)][c];                               \
        const f32x2 e0 = vexp2(qs0 * (kk + PNEW));                       \
        const f32x2 e1 = vexp2(qs1 * (kk + PH1));                        \
        const f32x2 e2 = vexp2(qs2 * (kk + PH2));                        \
        const f32x2 e3 = vexp2(qs3 * (kk + PH3));                        \
        d0 += e0; n0 += e0 * vv;                                         \
        d1 += e1; n1 += e1 * vv;                                         \
        d2 += e2; n2 += e2 * vv;                                         \
        d3 += e3; n3 += e3 * vv;                                         \
    }

// Edge-block variant: every term masked by m = (j in [0, L-1]); j shared by
// all 4 rows at a given step. Scalar m broadcasts over the vector.
#define STEP4E(T, PNEW, PH1, PH2, PH3)                                   \
    {                                                                    \
        const int jj = iA - S_ + (T);                                    \
        const float m = (jj >= 0 && jj <= L_ - 1) ? 1.f : 0.f;           \
        const int rl = rb + (T);                                         \
        const f32x2 kk = *(const f32x2*)&Kw[rl][c];                      \
        const f32x2 vv = *(const f32x2*)&Vw[rl][c];                      \
        PNEW = *(const f32x2*)&Pw[(T)][c];                               \
        const f32x2 e0 = m * vexp2(qs0 * (kk + PNEW));                   \
        const f32x2 e1 = m * vexp2(qs1 * (kk + PH1));                    \
        const f32x2 e2 = m * vexp2(qs2 * (kk + PH2));                    \
        const f32x2 e3 = m * vexp2(qs3 * (kk + PH3));                    \
        d0 += e0; n0 += e0 * vv;                                         \
        d1 += e1; n1 += e1 * vv;                                         \
        d2 += e2; n2 += e2 * vv;                                         \
        d3 += e3; n3 += e3 * vv;                                         \
    }

__global__ __launch_bounds__(128, 2) void aft_stage2h(
    const float* __restrict__ Q, const float* __restrict__ K,
    const float* __restrict__ V, const float* __restrict__ pb,
    float* __restrict__ out)
{
    __shared__ float Kw[HR7][PS7];        // 13824 B
    __shared__ float Vw[HR7][PS7];        // 13824 B
    __shared__ float Pw[2 * S_ + 1][PS7]; //  9360 B (total 37008 B, 4 blk/CU)

    const int tid = threadIdx.x;          // 0..127
    const int b  = blockIdx.y;
    const int i0 = blockIdx.x * TI7;
    const int c0 = blockIdx.z * CH7;

    const int duo = tid & 15;             // channel duo 0..15
    const int qd  = tid >> 4;             // row quad 0..7
    const int c   = duo * 2;
    const int iA  = i0 + qd * 4;          // rows iA .. iA+3
    const int rb  = qd * 4;               // LDS row of j = iA - S at t=0

    // Q reads issued before staging; complete under the barrier.
    const float* Qr = Q + ((size_t)b * L_ + iA) * E_ + c0 + c;
    const f32x2 qv0 = *(const f32x2*)(Qr);
    const f32x2 qv1 = *(const f32x2*)(Qr + E_);
    const f32x2 qv2 = *(const f32x2*)(Qr + 2 * E_);
    const f32x2 qv3 = *(const f32x2*)(Qr + 3 * E_);

    const float* Kb = K + (size_t)b * L_ * E_;
    const float* Vb = V + (size_t)b * L_ * E_;

    // ---- stage K/V halo rows (96 rows x 32 ch), 128 threads ----
    for (int idx = tid; idx < HR7 * 8; idx += 128) {
        const int r = idx >> 3;
        const int cc = (idx & 7) * 4;
        int j = i0 - S_ + r;
        j = j < 0 ? 0 : (j > L_ - 1 ? L_ - 1 : j);   // clamped rows are masked
        const size_t g = (size_t)j * E_ + c0 + cc;
        *(float4*)&Kw[r][cc] = *(const float4*)(Kb + g);
        *(float4*)&Vw[r][cc] = *(const float4*)(Vb + g);
    }
    // ---- stage pos_bias slice (65 rows x 32 ch) ----
    for (int idx = tid; idx < (2 * S_ + 1) * 8; idx += 128) {
        const int r = idx >> 3;
        const int cc = (idx & 7) * 4;
        *(float4*)&Pw[r][cc] = *(const float4*)(pb + (size_t)r * E_ + c0 + cc);
    }
    __syncthreads();

    const float LOG2E = 1.44269504088896340736f;
    const f32x2 qs0 = qv0 * LOG2E;
    const f32x2 qs1 = qv1 * LOG2E;
    const f32x2 qs2 = qv2 * LOG2E;
    const f32x2 qs3 = qv3 * LOG2E;

    f32x2 d0 = {0.f, 0.f}, n0 = {0.f, 0.f};
    f32x2 d1 = {0.f, 0.f}, n1 = {0.f, 0.f};
    f32x2 d2 = {0.f, 0.f}, n2 = {0.f, 0.f};
    f32x2 d3 = {0.f, 0.f}, n3 = {0.f, 0.f};

    f32x2 p0, h1, h2, h3;

    const bool interior = (blockIdx.x >= 1) && (blockIdx.x <= (L_ / TI7) - 2);

    if (interior) {
        // ---- head t=0..3: w=0 peels (e=1) + early regular taps ----
        {   // t=0: row0 peel only
            const f32x2 vv = *(const f32x2*)&Vw[rb][c];
            d0 += 1.f; n0 += vv;
        }
        {   // t=1: row0 w=1; row1 peel
            const f32x2 kk = *(const f32x2*)&Kw[rb + 1][c];
            const f32x2 vv = *(const f32x2*)&Vw[rb + 1][c];
            h3 = *(const f32x2*)&Pw[1][c];               // P[1]
            const f32x2 e0 = vexp2(qs0 * (kk + h3));
            d0 += e0; n0 += e0 * vv;
            d1 += 1.f; n1 += vv;
        }
        {   // t=2: row0 w=2; row1 w=1; row2 peel
            const f32x2 kk = *(const f32x2*)&Kw[rb + 2][c];
            const f32x2 vv = *(const f32x2*)&Vw[rb + 2][c];
            h2 = *(const f32x2*)&Pw[2][c];               // P[2]
            const f32x2 e0 = vexp2(qs0 * (kk + h2));
            const f32x2 e1 = vexp2(qs1 * (kk + h3));
            d0 += e0; n0 += e0 * vv;
            d1 += e1; n1 += e1 * vv;
            d2 += 1.f; n2 += vv;
        }
        {   // t=3: row0 w=3; row1 w=2; row2 w=1; row3 peel
            const f32x2 kk = *(const f32x2*)&Kw[rb + 3][c];
            const f32x2 vv = *(const f32x2*)&Vw[rb + 3][c];
            h1 = *(const f32x2*)&Pw[3][c];               // P[3]
            const f32x2 e0 = vexp2(qs0 * (kk + h1));
            const f32x2 e1 = vexp2(qs1 * (kk + h2));
            const f32x2 e2 = vexp2(qs2 * (kk + h3));
            d0 += e0; n0 += e0 * vv;
            d1 += e1; n1 += e1 * vv;
            d2 += e2; n2 += e2 * vv;
            d3 += 1.f; n3 += vv;
        }
        // entry invariant: h1=P[t-1], h2=P[t-2], h3=P[t-3]
#pragma unroll 2
        for (int t = 4; t <= 60; t += 4) {
            STEP4I(t + 0, p0, h1, h2, h3)
            STEP4I(t + 1, h3, p0, h1, h2)
            STEP4I(t + 2, h2, h3, p0, h1)
            STEP4I(t + 3, h1, h2, h3, p0)
        }
        // after loop: h1=P[63], h2=P[62], h3=P[61]
        // ---- tail t=64..67: w=64 peels (e=1) + late regular taps ----
        {   // t=64: row0 peel; row1 w=63(h1); row2 w=62(h2); row3 w=61(h3)
            const f32x2 kk = *(const f32x2*)&Kw[rb + 64][c];
            const f32x2 vv = *(const f32x2*)&Vw[rb + 64][c];
            const f32x2 e1 = vexp2(qs1 * (kk + h1));
            const f32x2 e2 = vexp2(qs2 * (kk + h2));
            const f32x2 e3 = vexp2(qs3 * (kk + h3));
            d0 += 1.f; n0 += vv;
            d1 += e1; n1 += e1 * vv;
            d2 += e2; n2 += e2 * vv;
            d3 += e3; n3 += e3 * vv;
        }
        {   // t=65: row1 peel; row2 w=63(h1); row3 w=62(h2)
            const f32x2 kk = *(const f32x2*)&Kw[rb + 65][c];
            const f32x2 vv = *(const f32x2*)&Vw[rb + 65][c];
            const f32x2 e2 = vexp2(qs2 * (kk + h1));
            const f32x2 e3 = vexp2(qs3 * (kk + h2));
            d1 += 1.f; n1 += vv;
            d2 += e2; n2 += e2 * vv;
            d3 += e3; n3 += e3 * vv;
        }
        {   // t=66: row2 peel; row3 w=63(h1)
            const f32x2 kk = *(const f32x2*)&Kw[rb + 66][c];
            const f32x2 vv = *(const f32x2*)&Vw[rb + 66][c];
            const f32x2 e3 = vexp2(qs3 * (kk + h1));
            d2 += 1.f; n2 += vv;
            d3 += e3; n3 += e3 * vv;
        }
        {   // t=67: row3 peel
            const f32x2 vv = *(const f32x2*)&Vw[rb + 67][c];
            d3 += 1.f; n3 += vv;
        }
    } else {
        // ---- edge blocks: every step masked by j-validity (shared by rows) ----
        {   // t=0: row0 peel
            const int jj = iA - S_;
            const float m = (jj >= 0) ? 1.f : 0.f;
            const f32x2 vv = *(const f32x2*)&Vw[rb][c];
            d0 += m; n0 += m * vv;
        }
        {   // t=1
            const int jj = iA - S_ + 1;
            const float m = (jj >= 0 && jj <= L_ - 1) ? 1.f : 0.f;
            const f32x2 kk = *(const f32x2*)&Kw[rb + 1][c];
            const f32x2 vv = *(const f32x2*)&Vw[rb + 1][c];
            h3 = *(const f32x2*)&Pw[1][c];
            const f32x2 e0 = m * vexp2(qs0 * (kk + h3));
            d0 += e0; n0 += e0 * vv;
            d1 += m;  n1 += m * vv;
        }
        {   // t=2
            const int jj = iA - S_ + 2;
            const float m = (jj >= 0 && jj <= L_ - 1) ? 1.f : 0.f;
            const f32x2 kk = *(const f32x2*)&Kw[rb + 2][c];
            const f32x2 vv = *(const f32x2*)&Vw[rb + 2][c];
            h2 = *(const f32x2*)&Pw[2][c];
            const f32x2 e0 = m * vexp2(qs0 * (kk + h2));
            const f32x2 e1 = m * vexp2(qs1 * (kk + h3));
            d0 += e0; n0 += e0 * vv;
            d1 += e1; n1 += e1 * vv;
            d2 += m;  n2 += m * vv;
        }
        {   // t=3
            const int jj = iA - S_ + 3;
            const float m = (jj >= 0 && jj <= L_ - 1) ? 1.f : 0.f;
            const f32x2 kk = *(const f32x2*)&Kw[rb + 3][c];
            const f32x2 vv = *(const f32x2*)&Vw[rb + 3][c];
            h1 = *(const f32x2*)&Pw[3][c];
            const f32x2 e0 = m * vexp2(qs0 * (kk + h1));
            const f32x2 e1 = m * vexp2(qs1 * (kk + h2));
            const f32x2 e2 = m * vexp2(qs2 * (kk + h3));
            d0 += e0; n0 += e0 * vv;
            d1 += e1; n1 += e1 * vv;
            d2 += e2; n2 += e2 * vv;
            d3 += m;  n3 += m * vv;
        }
#pragma unroll 2
        for (int t = 4; t <= 60; t += 4) {
            STEP4E(t + 0, p0, h1, h2, h3)
            STEP4E(t + 1, h3, p0, h1, h2)
            STEP4E(t + 2, h2, h3, p0, h1)
            STEP4E(t + 3, h1, h2, h3, p0)
        }
        {   // t=64
            const int jj = iA - S_ + 64;
            const float m = (jj >= 0 && jj <= L_ - 1) ? 1.f : 0.f;
            const f32x2 kk = *(const f32x2*)&Kw[rb + 64][c];
            const f32x2 vv = *(const f32x2*)&Vw[rb + 64][c];
            const f32x2 e1 = m * vexp2(qs1 * (kk + h1));
            const f32x2 e2 = m * vexp2(qs2 * (kk + h2));
            const f32x2 e3 = m * vexp2(qs3 * (kk + h3));
            d0 += m;  n0 += m * vv;
            d1 += e1; n1 += e1 * vv;
            d2 += e2; n2 += e2 * vv;
            d3 += e3; n3 += e3 * vv;
        }
        {   // t=65
            const int jj = iA - S_ + 65;
            const float m = (jj >= 0 && jj <= L_ - 1) ? 1.f : 0.f;
            const f32x2 kk = *(const f32x2*)&Kw[rb + 65][c];
            const f32x2 vv = *(const f32x2*)&Vw[rb + 65][c];
            const f32x2 e2 = m * vexp2(qs2 * (kk + h1));
            const f32x2 e3 = m * vexp2(qs3 * (kk + h2));
            d1 += m;  n1 += m * vv;
            d2 += e2; n2 += e2 * vv;
            d3 += e3; n3 += e3 * vv;
        }
        {   // t=66
            const int jj = iA - S_ + 66;
            const float m = (jj >= 0 && jj <= L_ - 1) ? 1.f : 0.f;
            const f32x2 kk = *(const f32x2*)&Kw[rb + 66][c];
            const f32x2 vv = *(const f32x2*)&Vw[rb + 66][c];
            const f32x2 e3 = m * vexp2(qs3 * (kk + h1));
            d2 += m;  n2 += m * vv;
            d3 += e3; n3 += e3 * vv;
        }
        {   // t=67
            const int jj = iA - S_ + 67;
            const float m = (jj >= 0 && jj <= L_ - 1) ? 1.f : 0.f;
            const f32x2 vv = *(const f32x2*)&Vw[rb + 67][c];
            d3 += m; n3 += m * vv;
        }
    }

    // sigmoid via raw exp2 (reuse qs = q*log2e): sig = 1/(1+2^-qs)
    f32x2 s0, s1, s2, s3;
    s0.x = 1.f / (1.f + fexp2(-qs0.x)); s0.y = 1.f / (1.f + fexp2(-qs0.y));
    s1.x = 1.f / (1.f + fexp2(-qs1.x)); s1.y = 1.f / (1.f + fexp2(-qs1.y));
    s2.x = 1.f / (1.f + fexp2(-qs2.x)); s2.y = 1.f / (1.f + fexp2(-qs2.y));
    s3.x = 1.f / (1.f + fexp2(-qs3.x)); s3.y = 1.f / (1.f + fexp2(-qs3.y));

    float* ob = out + ((size_t)b * L_ + iA) * E_ + c0 + c;
    *(f32x2*)(ob)          = s0 * s0 * n0 / d0;
    *(f32x2*)(ob + E_)     = s1 * s1 * n1 / d1;
    *(f32x2*)(ob + 2 * E_) = s2 * s2 * n2 / d2;
    *(f32x2*)(ob + 3 * E_) = s3 * s3 * n3 / d3;
}

// ===========================================================================
// PATH B (ws too small; fallback only): fully fused, fp32.
// ===========================================================================
#define TI 32
#define CG 64
#define RK 96
#define LDP 68

__global__ __launch_bounds__(256) void aft_fused(
    const float* __restrict__ q,
    const float* __restrict__ Wq, const float* __restrict__ bq,
    const float* __restrict__ Wk, const float* __restrict__ bk,
    const float* __restrict__ Wv, const float* __restrict__ bv,
    const float* __restrict__ pb,
    float* __restrict__ out)
{
    __shared__ float Kl[RK][LDP];
    __shared__ float Vl[RK][LDP];
    __shared__ float Ql[TI][LDP];

    const int i0 = blockIdx.x * TI;
    const int b  = blockIdx.y;
    const int c0 = blockIdx.z * CG;

    const int wave = threadIdx.x >> 6;
    const int lane = threadIdx.x & 63;
    const int rsel = lane & 15;
    const int koff = (lane >> 4) * 8;

    const float* qb = q + (size_t)b * L_ * E_;

    for (int job = wave; job < 56; job += 4) {
        int p, rt, ct;
        if (job < 24)      { p = 0; rt = job >> 2;        ct = job & 3; }
        else if (job < 48) { p = 1; rt = (job - 24) >> 2; ct = (job - 24) & 3; }
        else               { p = 2; rt = (job - 48) >> 2; ct = (job - 48) & 3; }

        int jrow = (p == 2) ? (i0 + rt * 16 + rsel)
                            : (i0 - S_ + rt * 16 + rsel);
        int jc = jrow < 0 ? 0 : (jrow > L_ - 1 ? L_ - 1 : jrow);
        const float* pa = qb + (size_t)jc * E_ + koff;

        const float* Wm = (p == 0) ? Wk : (p == 1) ? Wv : Wq;
        const float* bm = (p == 0) ? bk : (p == 1) ? bv : bq;
        const int n = c0 + ct * 16 + rsel;
        const float* pw = Wm + (size_t)n * E_ + koff;

        f32x4 acc = {0.f, 0.f, 0.f, 0.f};
#pragma unroll
        for (int k0 = 0; k0 < 256; k0 += 32) {
            bf16x8 ah, al, bh, bl;
            load8split(pa + k0, ah, al);
            load8split(pw + k0, bh, bl);
            acc = __builtin_amdgcn_mfma_f32_16x16x32_bf16(ah, bh, acc, 0, 0, 0);
            acc = __builtin_amdgcn_mfma_f32_16x16x32_bf16(ah, bl, acc, 0, 0, 0);
            acc = __builtin_amdgcn_mfma_f32_16x16x32_bf16(al, bh, acc, 0, 0, 0);
        }

        const float bias = bm[n];
        const int row0 = rt * 16 + (lane >> 4) * 4;
        const int colc = ct * 16 + rsel;
        float* dst = (p == 0) ? &Kl[0][0] : (p == 1) ? &Vl[0][0] : &Ql[0][0];
#pragma unroll
        for (int r = 0; r < 4; ++r)
            dst[(size_t)(row0 + r) * LDP + colc] = acc[r] + bias;
    }
    __syncthreads();

    const int cq  = threadIdx.x & 15;
    const int is0 = threadIdx.x >> 4;
    const int cL  = cq * 4;
    const int cG  = c0 + cL;
    const float* pbc = pb + cG;

    for (int rr = is0; rr < TI; rr += 16) {
        const int i = i0 + rr;
        const float4 qv = *(const float4*)&Ql[rr][cL];

        float den0 = 0.f, den1 = 0.f, den2 = 0.f, den3 = 0.f;
        float num0 = 0.f, num1 = 0.f, num2 = 0.f, num3 = 0.f;

        const int jlo = (i - S_ < 0) ? 0 : (i - S_);
        const int jhi = (i + S_ > L_ - 1) ? (L_ - 1) : (i + S_);

        for (int j = jlo; j <= jhi; ++j) {
            const int r = j - (i0 - S_);
            const int w = j - i + S_;
            const float4 vv = *(const float4*)&Vl[r][cL];

            float kx = 0.f, ky = 0.f, kz = 0.f, kw = 0.f;
            if (w != 0 && w != 2 * S_) {
                const float4 kk = *(const float4*)&Kl[r][cL];
                const float4 pp = *(const float4*)(pbc + (size_t)w * E_);
                kx = kk.x + pp.x;
                ky = kk.y + pp.y;
                kz = kk.z + pp.z;
                kw = kk.w + pp.w;
            }
            const float e0 = __expf(qv.x * kx);
            const float e1 = __expf(qv.y * ky);
            const float e2 = __expf(qv.z * kz);
            const float e3 = __expf(qv.w * kw);
            den0 += e0; den1 += e1; den2 += e2; den3 += e3;
            num0 += e0 * vv.x; num1 += e1 * vv.y;
            num2 += e2 * vv.z; num3 += e3 * vv.w;
        }

        const float s0 = 1.f / (1.f + __expf(-qv.x));
        const float s1 = 1.f / (1.f + __expf(-qv.y));
        const float s2 = 1.f / (1.f + __expf(-qv.z));
        const float s3 = 1.f / (1.f + __expf(-qv.w));

        float4 o;
        o.x = s0 * s0 * num0 / den0;
        o.y = s1 * s1 * num1 / den1;
        o.z = s2 * s2 * num2 / den2;
        o.w = s3 * s3 * num3 / den3;
        *(float4*)(out + ((size_t)b * L_ + i) * E_ + cG) = o;
    }
}

extern "C" void kernel_launch(void* const* d_in, const int* in_sizes, int n_in,
                              void* d_out, int out_size, void* d_ws, size_t ws_size,
                              hipStream_t stream) {
    const float* q  = (const float*)d_in[0];
    const float* Wq = (const float*)d_in[1];
    const float* bq = (const float*)d_in[2];
    const float* Wk = (const float*)d_in[3];
    const float* bk = (const float*)d_in[4];
    const float* Wv = (const float*)d_in[5];
    const float* bv = (const float*)d_in[6];
    const float* pb = (const float*)d_in[7];

    const size_t needA = (size_t)3 * 4096 * 256 * sizeof(float);  // 12.6 MB

    if (ws_size >= needA) {
        float* Qf = (float*)d_ws;
        float* Kf = Qf + (size_t)4096 * 256;
        float* Vf = Kf + (size_t)4096 * 256;
        qkv_gemm2<<<dim3(128, 1, 3), 256, 0, stream>>>(q, Wq, bq, Wk, bk, Wv, bv,
                                                       Qf, Kf, Vf);
        aft_stage2h<<<dim3(L_ / TI7, B_, E_ / CH7), 128, 0, stream>>>(
            Qf, Kf, Vf, pb, (float*)d_out);
    } else {
        aft_fused<<<dim3(L_ / TI, B_, E_ / CG), 256, 0, stream>>>(
            q, Wq, bq, Wk, bk, Wv, bv, pb, (float*)d_out);
    }
}